// Round 1
// baseline (373.971 us; speedup 1.0000x reference)
//
#include <hip/hip_runtime.h>

// MACE layer, fp32 I/O. N=20000, E=320000, F=64, P=5, R=8, H=64, S=10.
// R9: receiver-sorted edge processing.
//   Theory: kedge2's WRITE_SIZE (160 MB) == exact atomic payload -> fp16 atomics
//   write through to HBM and serialize at the coherence point. Counting-sort edges
//   by receiver (hist folded into knodeA2, kscan 1 block, kscat), then kedge2
//   accumulates per-receiver segments in fp32 registers and flushes one pair of
//   v2f16 atomics per distinct receiver per wave (~8x fewer atomics).
// Dispatch chain 6 launches:
//   kprep   : block 0 = species bucketing; blocks 1..62 = weight swizzles; all
//             blocks zero ecnt[20000].
//   knodeA2 : zero Ah + receiver histogram (global atomics) + s1/v1 MFMA GEMM.
//   kscan   : exclusive prefix over ecnt -> cursor bases (single block).
//   kscat   : eperm[atomicAdd(cursor[rcv])] = e  (receiver-sorted edge ids).
//   kedge2  : MFMA tw-GEMM + TP; edges via eperm; register accum + flush-on-
//             receiver-change packed-fp16 atomics.
//   knodeC2 : unchanged (MFMA + species-sorted tiles).
#define NNODES 20000
#define NEDGES 320000
#define NTILES 1260

typedef __attribute__((ext_vector_type(8))) short short8;    // 8 bf16
typedef __attribute__((ext_vector_type(4))) float float4v;   // 16 B
typedef _Float16 half2v __attribute__((ext_vector_type(2))); // packed fp16

// fragment-pool chunk offsets (1 chunk = 8 bf16 = 16 B)
#define CW2   0
#define CWls  2560
#define CWlv  3072
#define CWis  3584
#define CWiv  4096
#define CWps  4608
#define CWpv  5120
#define CWss  5632
#define CWsv  10752
#define NCHUNK_TOT 15872     // 2560 + 6*512 + 2*5120

__device__ __forceinline__ float bitsf(unsigned u){ union{unsigned u; float f;} x; x.u=u; return x.f; }
__device__ __forceinline__ float b2f(unsigned short u){ return bitsf(((unsigned)u)<<16); }
__device__ __forceinline__ unsigned short f2b(float f){
    union{float f; unsigned u;} x; x.f=f;
    unsigned r = x.u + 0x7fffu + ((x.u>>16)&1u);   // RNE
    return (unsigned short)(r>>16);
}
__device__ __forceinline__ short8 pack8(const float* f){
    short8 r;
    #pragma unroll
    for (int j=0;j<8;++j) r[j] = (short)f2b(f[j]);
    return r;
}

__constant__ float kINV_SQRT3 = 0.5773502691896258f;
__constant__ float kINV_SQRT2 = 0.7071067811865476f;
__constant__ float kINV_AVG   = 0.25f;             // 1/sqrt(16)

// ---- merged prep: bucketing (block 0) + all weight swizzles (blocks 1..62) --------------
__global__ __launch_bounds__(256) void kprep(
    const int* __restrict__ specie,
    const float* __restrict__ Wr2,
    const float* __restrict__ Wls, const float* __restrict__ Wlv,
    const float* __restrict__ Wis, const float* __restrict__ Wiv,
    const float* __restrict__ Wps, const float* __restrict__ Wpv,
    const float* __restrict__ Wss, const float* __restrict__ Wsv,
    unsigned short* __restrict__ P,
    int* __restrict__ perm, int* __restrict__ tspec,
    int* __restrict__ ecnt)
{
    const int tid = threadIdx.x;
    // zero the receiver-histogram (consumed by knodeA2's histogram pass)
    for (int i = blockIdx.x*256 + tid; i < NNODES; i += 63*256) ecnt[i] = 0;

    if (blockIdx.x == 0){
        __shared__ int cnt[10], base[10], ntl[10], cur[10];
        if (tid < 10) cnt[tid] = 0;
        __syncthreads();
        for (int n = tid; n < NNODES; n += 256) atomicAdd(&cnt[specie[n]], 1);
        __syncthreads();
        if (tid == 0){
            int b = 0;
            for (int sp = 0; sp < 10; ++sp){
                base[sp] = b; cur[sp] = b;
                ntl[sp] = (cnt[sp] + 15) >> 4;
                b += ntl[sp] << 4;
            }
        }
        __syncthreads();
        for (int i = tid; i < NTILES*16; i += 256) perm[i] = -1;
        for (int t = tid; t < NTILES; t += 256){
            int sp = 0;
            #pragma unroll
            for (int k = 0; k < 10; ++k)
                if (t >= (base[k] >> 4) && t < (base[k] >> 4) + ntl[k]) sp = k;
            tspec[t] = sp;
        }
        __syncthreads();
        for (int n = tid; n < NNODES; n += 256){
            int slot = atomicAdd(&cur[specie[n]], 1);
            perm[slot] = n;
        }
        return;
    }
    // swizzle blocks: 62 x 256 = 15872 chunks, one each
    const int c = (blockIdx.x - 1)*256 + tid;
    if (c >= NCHUNK_TOT) return;
    unsigned short t[8];
    if (c < 2560){
        const int nt = c >> 7, ks = (c >> 6) & 1, ln = c & 63;
        const int col = nt*16 + (ln & 15);
        const int jb  = ks*32 + ((ln >> 4) & 3)*8;
        #pragma unroll
        for (int jj = 0; jj < 8; ++jj) t[jj] = f2b(Wr2[(jb+jj)*320 + col]);
    } else {
        int c2 = c - 2560;
        const float* src;
        if      (c2 <  512){ src = Wls; }
        else if (c2 < 1024){ src = Wlv; c2 -= 512; }
        else if (c2 < 1536){ src = Wis; c2 -= 1024; }
        else if (c2 < 2048){ src = Wiv; c2 -= 1536; }
        else if (c2 < 2560){ src = Wps; c2 -= 2048; }
        else if (c2 < 3072){ src = Wpv; c2 -= 2560; }
        else if (c2 < 8192){ src = Wss; c2 -= 3072; }
        else               { src = Wsv; c2 -= 8192; }
        const int grp = c2 >> 9, loc = c2 & 511;
        const int nt = loc >> 7, ks = (loc >> 6) & 1, ln = loc & 63;
        const int col  = nt*16 + (ln & 15);
        const int row0 = grp*64 + ks*32 + ((ln>>4)&3)*8;
        #pragma unroll
        for (int jj = 0; jj < 8; ++jj) t[jj] = f2b(src[(row0+jj)*64 + col]);
    }
    unsigned* d = (unsigned*)(P + (size_t)c*8);
    d[0] = (unsigned)t[0] | ((unsigned)t[1]<<16);
    d[1] = (unsigned)t[2] | ((unsigned)t[3]<<16);
    d[2] = (unsigned)t[4] | ((unsigned)t[5]<<16);
    d[3] = (unsigned)t[6] | ((unsigned)t[7]<<16);
}

// ---- Kernel A (MFMA): zero Ah, receiver histogram, then s1 = s@Wls, v1 = v@Wlv ----------
__global__ __launch_bounds__(256) void knodeA2(
    const float* __restrict__ s, const float* __restrict__ v,
    const unsigned short* __restrict__ P,
    const int* __restrict__ receivers, int* __restrict__ ecnt,
    unsigned short* __restrict__ s1, unsigned short* __restrict__ v1,
    float4v* __restrict__ AhZ)
{
    // zero the fp16 accumulator (NNODES*128 dwords = 640000 float4)
    float4v zz = {0.f,0.f,0.f,0.f};
    for (int i = blockIdx.x*256 + threadIdx.x; i < NNODES*32; i += 313*256) AhZ[i] = zz;
    // receiver histogram for the edge counting-sort (ecnt zeroed by kprep)
    for (int e = blockIdx.x*256 + threadIdx.x; e < NEDGES; e += 313*256)
        atomicAdd(&ecnt[receivers[e]], 1);

    const int w = threadIdx.x >> 6, lane = threadIdx.x & 63;
    const int t = blockIdx.x*4 + w;
    if (t >= 1250) return;
    const int mcol = lane & 15, quad = lane >> 4;
    const int node = t*16 + mcol;
    const short8* PB = (const short8*)P;

    short8 fS[2], fV[3][2];
    #pragma unroll
    for (int ks = 0; ks < 2; ++ks){
        const int k0 = ks*32 + quad*8;
        float ts[8];
        { float4v a = *(const float4v*)&s[node*64 + k0];
          float4v b = *(const float4v*)&s[node*64 + k0 + 4];
          #pragma unroll
          for (int j = 0; j < 4; ++j){ ts[j] = a[j]; ts[4+j] = b[j]; } }
        fS[ks] = pack8(ts);
        float tv[24];
        #pragma unroll
        for (int q = 0; q < 6; ++q){
            float4v x = *(const float4v*)&v[(node*64 + k0)*3 + q*4];
            #pragma unroll
            for (int j = 0; j < 4; ++j) tv[q*4+j] = x[j];
        }
        #pragma unroll
        for (int c = 0; c < 3; ++c){
            float tc[8];
            #pragma unroll
            for (int j = 0; j < 8; ++j) tc[j] = tv[j*3 + c];
            fV[c][ks] = pack8(tc);
        }
    }
    float4v z = {0.f,0.f,0.f,0.f};
    #pragma unroll
    for (int nt = 0; nt < 4; ++nt){
        float4v aS = __builtin_amdgcn_mfma_f32_16x16x32_bf16(fS[0], PB[CWls+(nt*2+0)*64+lane], z, 0,0,0);
        aS = __builtin_amdgcn_mfma_f32_16x16x32_bf16(fS[1], PB[CWls+(nt*2+1)*64+lane], aS, 0,0,0);
        float4v aV[3];
        #pragma unroll
        for (int c = 0; c < 3; ++c){
            aV[c] = __builtin_amdgcn_mfma_f32_16x16x32_bf16(fV[c][0], PB[CWlv+(nt*2+0)*64+lane], z, 0,0,0);
            aV[c] = __builtin_amdgcn_mfma_f32_16x16x32_bf16(fV[c][1], PB[CWlv+(nt*2+1)*64+lane], aV[c], 0,0,0);
        }
        const int g = nt*16 + mcol;
        #pragma unroll
        for (int r = 0; r < 4; ++r){
            const int nr = t*16 + quad*4 + r;
            s1[nr*64 + g] = f2b(aS[r]);
            #pragma unroll
            for (int c = 0; c < 3; ++c) v1[(nr*3+c)*64 + g] = f2b(aV[c][r]);
        }
    }
}

// ---- counting-sort step 2: exclusive prefix sum over ecnt (in place -> cursor) ----------
__global__ __launch_bounds__(256) void kscan(int* __restrict__ ecnt)
{
    __shared__ int part[256];
    const int tid  = threadIdx.x;
    const int base = tid*79;               // 256*79 = 20224 >= 20000
    int sum = 0;
    #pragma unroll 1
    for (int i = 0; i < 79; ++i){
        int idx = base + i;
        if (idx < NNODES) sum += ecnt[idx];
    }
    part[tid] = sum;
    __syncthreads();
    if (tid == 0){
        int acc = 0;
        #pragma unroll 1
        for (int i = 0; i < 256; ++i){ int c = part[i]; part[i] = acc; acc += c; }
    }
    __syncthreads();
    int run = part[tid];
    #pragma unroll 1
    for (int i = 0; i < 79; ++i){
        int idx = base + i;
        if (idx < NNODES){ int c = ecnt[idx]; ecnt[idx] = run; run += c; }
    }
}

// ---- counting-sort step 3: scatter edge ids into receiver-sorted order ------------------
__global__ __launch_bounds__(256) void kscat(
    const int* __restrict__ receivers, int* __restrict__ ecur, int* __restrict__ eperm)
{
    const int e = blockIdx.x*256 + threadIdx.x;
    if (e >= NEDGES) return;
    const int pos = atomicAdd(&ecur[receivers[e]], 1);
    eperm[pos] = e;
}

// ---- Kernel B: layer1 -> MFMA tw-GEMM -> TP -> segment-accumulated fp16 atomics ---------
__global__ __launch_bounds__(256) void kedge2(
    const float* __restrict__ Y1, const float* __restrict__ ef,
    const int* __restrict__ senders, const int* __restrict__ receivers,
    const float* __restrict__ Wr1, const unsigned short* __restrict__ W2s,
    const unsigned short* __restrict__ s1, const unsigned short* __restrict__ v1,
    const int* __restrict__ eperm,
    half2v* __restrict__ Ah)
{
    __shared__ unsigned short hlds[64*72];
    __shared__ unsigned short twlds[64*330];
    const int lane = threadIdx.x & 63;
    const int w    = threadIdx.x >> 6;
    const int ew   = blockIdx.x*64 + w*16;

    // wave's 16 receiver-sorted edge ids live in lanes 0..15
    int epreg = 0;
    if (lane < 16) epreg = eperm[ew + lane];
    // each lane gathers 2 radial feats of edge (lane>>2): full 8 feats per edge over 4 lanes
    const int  eme = __shfl(epreg, lane >> 2);
    const float efa = ef[eme*8 + (lane&3)*2];
    const float efb = ef[eme*8 + (lane&3)*2 + 1];

    float w1r[8];
    #pragma unroll
    for (int r = 0; r < 8; ++r) w1r[r] = Wr1[r*64 + lane];

    float y0r = 0.f, y1r = 0.f, y2r = 0.f;
    int   sndreg = 0, rcvreg = 0;
    if (lane < 16){
        y0r = Y1[epreg*3 + 0];
        y1r = Y1[epreg*3 + 1];
        y2r = Y1[epreg*3 + 2];
        sndreg = senders[epreg];
        rcvreg = receivers[epreg];
    }

    #pragma unroll
    for (int e16 = 0; e16 < 16; ++e16){
        float hj = 0.f;
        #pragma unroll
        for (int r = 0; r < 8; ++r)
            hj += __shfl((r&1) ? efb : efa, e16*4 + (r>>1)) * w1r[r];
        hj = hj / (1.f + __expf(-hj));
        hlds[(w*16 + e16)*72 + lane] = f2b(hj);
    }
    __syncthreads();

    short8 a0 = *(const short8*)&hlds[(w*16 + (lane&15))*72 +      (lane>>4)*8];
    short8 a1 = *(const short8*)&hlds[(w*16 + (lane&15))*72 + 32 + (lane>>4)*8];
    float4v acc[20];
    #pragma unroll
    for (int nt = 0; nt < 20; ++nt){
        short8 b0 = *(const short8*)&W2s[((nt*2+0)*64 + lane)*8];
        short8 b1 = *(const short8*)&W2s[((nt*2+1)*64 + lane)*8];
        float4v z = {0.f, 0.f, 0.f, 0.f};
        acc[nt] = __builtin_amdgcn_mfma_f32_16x16x32_bf16(a0, b0, z, 0, 0, 0);
        acc[nt] = __builtin_amdgcn_mfma_f32_16x16x32_bf16(a1, b1, acc[nt], 0, 0, 0);
    }
    #pragma unroll
    for (int nt = 0; nt < 20; ++nt){
        const int col = nt*16 + (lane & 15);
        #pragma unroll
        for (int r = 0; r < 4; ++r){
            const int erow = w*16 + (lane>>4)*4 + r;
            twlds[erow*330 + col] = f2b(acc[nt][r]);
        }
    }

    // edges are receiver-sorted: accumulate in fp32 regs, flush on receiver change
    int   cur = -1;
    float aS = 0.f, aV0 = 0.f, aV1 = 0.f, aV2 = 0.f;
    for (int e16 = 0; e16 < 16; ++e16){
        const int erow = w*16 + e16;
        float tw0 = b2f(twlds[erow*330 +   0 + lane]);
        float tw1 = b2f(twlds[erow*330 +  64 + lane]);
        float tw2 = b2f(twlds[erow*330 + 128 + lane]);
        float tw3 = b2f(twlds[erow*330 + 192 + lane]);
        float tw4 = b2f(twlds[erow*330 + 256 + lane]);
        const int snd = __shfl(sndreg, e16);
        const int rcv = __shfl(rcvreg, e16);
        float y0 = __shfl(y0r, e16);
        float y1 = __shfl(y1r, e16);
        float y2 = __shfl(y2r, e16);
        float ss  = b2f(s1[snd*64 + lane]);
        float vs0 = b2f(v1[(snd*3+0)*64 + lane]);
        float vs1 = b2f(v1[(snd*3+1)*64 + lane]);
        float vs2 = b2f(v1[(snd*3+2)*64 + lane]);
        float dot = vs0*y0 + vs1*y1 + vs2*y2;
        float c0 = vs1*y2 - vs2*y1;
        float c1 = vs2*y0 - vs0*y2;
        float c2 = vs0*y1 - vs1*y0;
        float ms  = tw0*ss + tw1*dot*kINV_SQRT3;
        float t2s = tw2*ss, t4 = tw4*kINV_SQRT2;
        float mv0 = t2s*y0 + tw3*vs0 + t4*c0;
        float mv1 = t2s*y1 + tw3*vs1 + t4*c1;
        float mv2 = t2s*y2 + tw3*vs2 + t4*c2;
        if (rcv != cur){                       // wave-uniform at runtime (sorted)
            if (cur >= 0){
                half2v p01 = { (_Float16)aS,  (_Float16)aV0 };
                half2v p23 = { (_Float16)aV1, (_Float16)aV2 };
                __builtin_amdgcn_global_atomic_fadd_v2f16(&Ah[cur*128 + lane],      p01);
                __builtin_amdgcn_global_atomic_fadd_v2f16(&Ah[cur*128 + 64 + lane], p23);
            }
            cur = rcv;
            aS = 0.f; aV0 = 0.f; aV1 = 0.f; aV2 = 0.f;
        }
        aS += ms; aV0 += mv0; aV1 += mv1; aV2 += mv2;
    }
    if (cur >= 0){
        half2v p01 = { (_Float16)aS,  (_Float16)aV0 };
        half2v p23 = { (_Float16)aV1, (_Float16)aV2 };
        __builtin_amdgcn_global_atomic_fadd_v2f16(&Ah[cur*128 + lane],      p01);
        __builtin_amdgcn_global_atomic_fadd_v2f16(&Ah[cur*128 + 64 + lane], p23);
    }
}

// ---- Kernel C (MFMA, species-sorted tiles; vectorized gathers) --------------------------
__global__ __launch_bounds__(256) void knodeC2(
    const float* __restrict__ s, const float* __restrict__ v,
    const half2v* __restrict__ Ah,
    const unsigned short* __restrict__ P,
    const int* __restrict__ perm, const int* __restrict__ tspec,
    const float* __restrict__ wps, const float* __restrict__ wpv,
    const float* __restrict__ Wread,
    float* __restrict__ out)
{
    __shared__ unsigned short Bt[4][4][16*72];
    const int w = threadIdx.x >> 6, lane = threadIdx.x & 63;
    const int t = blockIdx.x*4 + w;
    if (t >= NTILES) return;
    const int mcol = lane & 15, quad = lane >> 4;
    const int spec = tspec[t];
    const int nA   = perm[t*16 + mcol];
    const short8* PB = (const short8*)P;
    const int sb = CWss + spec*512, vb = CWsv + spec*512;

    short8 fAs[2], fAv[3][2], fS[2], fV[3][2];
    if (nA >= 0){
        #pragma unroll
        for (int ks = 0; ks < 2; ++ks){
            const int k0 = ks*32 + quad*8;
            half2v pa[8], pb[8];
            *(float4v*)&pa[0] = *(const float4v*)&Ah[nA*128 + k0];
            *(float4v*)&pa[4] = *(const float4v*)&Ah[nA*128 + k0 + 4];
            *(float4v*)&pb[0] = *(const float4v*)&Ah[nA*128 + 64 + k0];
            *(float4v*)&pb[4] = *(const float4v*)&Ah[nA*128 + 64 + k0 + 4];
            float as_[8], a0_[8], a1_[8], a2_[8];
            #pragma unroll
            for (int j = 0; j < 8; ++j){
                as_[j] = (float)pa[j].x; a0_[j] = (float)pa[j].y;
                a1_[j] = (float)pb[j].x; a2_[j] = (float)pb[j].y;
            }
            fAs[ks] = pack8(as_); fAv[0][ks] = pack8(a0_);
            fAv[1][ks] = pack8(a1_); fAv[2][ks] = pack8(a2_);
            float ts[8];
            { float4v a = *(const float4v*)&s[nA*64 + k0];
              float4v b = *(const float4v*)&s[nA*64 + k0 + 4];
              #pragma unroll
              for (int j = 0; j < 4; ++j){ ts[j] = a[j]; ts[4+j] = b[j]; } }
            fS[ks] = pack8(ts);
            float tv[24];
            #pragma unroll
            for (int q = 0; q < 6; ++q){
                float4v x = *(const float4v*)&v[(nA*64 + k0)*3 + q*4];
                #pragma unroll
                for (int j = 0; j < 4; ++j) tv[q*4+j] = x[j];
            }
            #pragma unroll
            for (int c = 0; c < 3; ++c){
                float tc[8];
                #pragma unroll
                for (int j = 0; j < 8; ++j) tc[j] = tv[j*3 + c];
                fV[c][ks] = pack8(tc);
            }
        }
    } else {
        short8 z8 = {};
        #pragma unroll
        for (int ks = 0; ks < 2; ++ks){
            fAs[ks] = z8; fS[ks] = z8;
            #pragma unroll
            for (int c = 0; c < 3; ++c){ fAv[c][ks] = z8; fV[c][ks] = z8; }
        }
    }

    float4v z = {0.f,0.f,0.f,0.f};
    float4v scS[4], scV[3][4];
    #pragma unroll
    for (int nt = 0; nt < 4; ++nt){
        float4v Ais = __builtin_amdgcn_mfma_f32_16x16x32_bf16(fAs[0], PB[CWis+(nt*2+0)*64+lane], z, 0,0,0);
        Ais = __builtin_amdgcn_mfma_f32_16x16x32_bf16(fAs[1], PB[CWis+(nt*2+1)*64+lane], Ais, 0,0,0);
        float4v Aiv[3];
        #pragma unroll
        for (int c = 0; c < 3; ++c){
            Aiv[c] = __builtin_amdgcn_mfma_f32_16x16x32_bf16(fAv[c][0], PB[CWiv+(nt*2+0)*64+lane], z, 0,0,0);
            Aiv[c] = __builtin_amdgcn_mfma_f32_16x16x32_bf16(fAv[c][1], PB[CWiv+(nt*2+1)*64+lane], Aiv[c], 0,0,0);
        }
        scS[nt] = __builtin_amdgcn_mfma_f32_16x16x32_bf16(fS[0], PB[sb+(nt*2+0)*64+lane], z, 0,0,0);
        scS[nt] = __builtin_amdgcn_mfma_f32_16x16x32_bf16(fS[1], PB[sb+(nt*2+1)*64+lane], scS[nt], 0,0,0);
        #pragma unroll
        for (int c = 0; c < 3; ++c){
            scV[c][nt] = __builtin_amdgcn_mfma_f32_16x16x32_bf16(fV[c][0], PB[vb+(nt*2+0)*64+lane], z, 0,0,0);
            scV[c][nt] = __builtin_amdgcn_mfma_f32_16x16x32_bf16(fV[c][1], PB[vb+(nt*2+1)*64+lane], scV[c][nt], 0,0,0);
        }
        const int g = nt*16 + mcol;
        float w0 = wps[spec*320 +   0 + g], w1 = wps[spec*320 +  64 + g];
        float w2 = wps[spec*320 + 128 + g], w3 = wps[spec*320 + 192 + g];
        float w4 = wps[spec*320 + 256 + g];
        float u0 = wpv[spec*256 +   0 + g], u1 = wpv[spec*256 +  64 + g];
        float u2 = wpv[spec*256 + 128 + g], u3 = wpv[spec*256 + 192 + g];
        #pragma unroll
        for (int r = 0; r < 4; ++r){
            float A  = Ais[r]    * kINV_AVG;
            float a0 = Aiv[0][r] * kINV_AVG;
            float a1 = Aiv[1][r] * kINV_AVG;
            float a2 = Aiv[2][r] * kINV_AVG;
            float d   = a0*a0 + a1*a1 + a2*a2;
            float as2 = A*A;
            float Bs  = w0*A + w1*as2 + w2*d + w3*as2*A + w4*A*d;
            float gg  = u0 + u1*A + u2*as2 + u3*d;
            const int row = quad*4 + r;
            Bt[w][0][row*72 + g] = f2b(Bs);
            Bt[w][1][row*72 + g] = f2b(gg*a0);
            Bt[w][2][row*72 + g] = f2b(gg*a1);
            Bt[w][3][row*72 + g] = f2b(gg*a2);
        }
    }

    short8 bS[2], bV[3][2];
    #pragma unroll
    for (int ks = 0; ks < 2; ++ks){
        bS[ks] = *(const short8*)&Bt[w][0][mcol*72 + ks*32 + quad*8];
        #pragma unroll
        for (int c = 0; c < 3; ++c)
            bV[c][ks] = *(const short8*)&Bt[w][1+c][mcol*72 + ks*32 + quad*8];
    }

    float* out_node = out;
    float* out_s    = out + NNODES;
    float* out_v    = out + NNODES + NNODES*64;
    int ndr[4];
    #pragma unroll
    for (int r = 0; r < 4; ++r) ndr[r] = perm[t*16 + quad*4 + r];
    float4v rd = {0.f,0.f,0.f,0.f};
    #pragma unroll
    for (int nt = 0; nt < 4; ++nt){
        float4v oS = scS[nt];
        oS = __builtin_amdgcn_mfma_f32_16x16x32_bf16(bS[0], PB[CWps+(nt*2+0)*64+lane], oS, 0,0,0);
        oS = __builtin_amdgcn_mfma_f32_16x16x32_bf16(bS[1], PB[CWps+(nt*2+1)*64+lane], oS, 0,0,0);
        float4v oV[3];
        #pragma unroll
        for (int c = 0; c < 3; ++c){
            oV[c] = scV[c][nt];
            oV[c] = __builtin_amdgcn_mfma_f32_16x16x32_bf16(bV[c][0], PB[CWpv+(nt*2+0)*64+lane], oV[c], 0,0,0);
            oV[c] = __builtin_amdgcn_mfma_f32_16x16x32_bf16(bV[c][1], PB[CWpv+(nt*2+1)*64+lane], oV[c], 0,0,0);
        }
        const int g = nt*16 + mcol;
        float wr = Wread[g];
        #pragma unroll
        for (int r = 0; r < 4; ++r){
            if (ndr[r] >= 0){
                out_s[ndr[r]*64 + g] = oS[r];
                #pragma unroll
                for (int c = 0; c < 3; ++c) out_v[(ndr[r]*64 + g)*3 + c] = oV[c][r];
            }
            rd[r] += oS[r] * wr;
        }
    }
    #pragma unroll
    for (int off = 1; off < 16; off <<= 1){
        #pragma unroll
        for (int r = 0; r < 4; ++r) rd[r] += __shfl_xor(rd[r], off);
    }
    if (mcol == 0){
        #pragma unroll
        for (int r = 0; r < 4; ++r) if (ndr[r] >= 0) out_node[ndr[r]] = rd[r];
    }
}

extern "C" void kernel_launch(void* const* d_in, const int* in_sizes, int n_in,
                              void* d_out, int out_size, void* d_ws, size_t ws_size,
                              hipStream_t stream)
{
    (void)in_sizes; (void)n_in; (void)out_size; (void)ws_size;
    const float* s    = (const float*)d_in[0];
    const float* v    = (const float*)d_in[1];
    const float* Y1   = (const float*)d_in[2];
    const float* ef   = (const float*)d_in[3];
    const int* specie = (const int*)d_in[4];
    const int* senders   = (const int*)d_in[5];
    const int* receivers = (const int*)d_in[6];
    const float* Wls  = (const float*)d_in[7];
    const float* Wlv  = (const float*)d_in[8];
    const float* Wss  = (const float*)d_in[9];
    const float* Wsv  = (const float*)d_in[10];
    const float* Wr1  = (const float*)d_in[11];
    const float* Wr2  = (const float*)d_in[12];
    const float* Wis  = (const float*)d_in[13];
    const float* Wiv  = (const float*)d_in[14];
    const float* wps  = (const float*)d_in[15];
    const float* wpv  = (const float*)d_in[16];
    const float* Wps  = (const float*)d_in[17];
    const float* Wpv  = (const float*)d_in[18];
    const float* Wrd  = (const float*)d_in[19];

    float* out = (float*)d_out;
    unsigned short* t_s1 = (unsigned short*)(out + NNODES);   // bf16 temp in d_out
    unsigned short* t_v1 = t_s1 + NNODES*64;
    // counting-sort scratch in the d_out tail (floats [2.60M, 2.95M)); consumed by
    // kedge2, then fully overwritten by knodeC2's out_v writes.
    int* ecnt  = (int*)(out + 2600000);    // 20000 ints  (histogram -> cursor)
    int* eperm = (int*)(out + 2624000);    // 320000 ints (receiver-sorted edge ids)

    // ws layout:
    //  [0, 253952)            bf16 fragment pool P
    //  [262144, +10.24M)      Ah fp16 accumulator [N][2][64] half2
    //  [10502144, +80640)     perm[20160]
    //  [10582784, +5040)      tspec[1260]
    char* ws = (char*)d_ws;
    unsigned short* P = (unsigned short*)ws;
    half2v* Ah  = (half2v*)(ws + 262144);
    int* perm   = (int*)(ws + 10502144);
    int* tspec  = (int*)(ws + 10582784);

    kprep<<<63, 256, 0, stream>>>(specie, Wr2, Wls, Wlv, Wis, Wiv, Wps, Wpv, Wss, Wsv,
                                  P, perm, tspec, ecnt);
    knodeA2<<<313, 256, 0, stream>>>(s, v, P, receivers, ecnt, t_s1, t_v1, (float4v*)Ah);
    kscan<<<1, 256, 0, stream>>>(ecnt);
    kscat<<<1250, 256, 0, stream>>>(receivers, ecnt, eperm);
    kedge2<<<5000, 256, 0, stream>>>(Y1, ef, senders, receivers, Wr1, P + CW2*8, t_s1, t_v1, eperm, Ah);
    knodeC2<<<315, 256, 0, stream>>>(s, v, Ah, P, perm, tspec, wps, wpv, Wrd, out);
}

// Round 3
// 329.722 us; speedup vs baseline: 1.1342x; 1.1342x over previous
//
#include <hip/hip_runtime.h>

// MACE layer, fp32 I/O. N=20000, E=320000, F=64, P=5, R=8, H=64, S=10.
// R11 = R8 (last deterministic-good, 331 us) + the validated R10 gather fix:
//   - knodeA2 emits packed sv1[node][chan][4] = {s1, v1x, v1y, v1z} bf16, so
//     kedge2's per-edge sender gather is ONE coalesced 8 B/lane load.
//   - kedge2 prefetches all 16 edges' sender rows into registers (T14) before
//     the silu/MFMA phases; TP loop is register-fed.
//   - Per-edge packed-fp16 atomics (R8 form): DETERMINISTIC addend set
//     (absmax 0.625 on two prior runs). The R9/R10 receiver-sort is dropped:
//     its racy kscat made the fp16 partial-sum rounding nondeterministic
//     (absmax 0.75 / 1.3125 across runs on equivalent code).
// Dispatch chain 4 launches: kprep -> knodeA2 -> kedge2 -> knodeC2.
#define NNODES 20000
#define NEDGES 320000
#define NTILES 1260

typedef __attribute__((ext_vector_type(8))) short short8;    // 8 bf16
typedef __attribute__((ext_vector_type(4))) float float4v;   // 16 B
typedef __attribute__((ext_vector_type(4))) unsigned short ushort4v; // 8 B
typedef _Float16 half2v __attribute__((ext_vector_type(2))); // packed fp16

// fragment-pool chunk offsets (1 chunk = 8 bf16 = 16 B)
#define CW2   0
#define CWls  2560
#define CWlv  3072
#define CWis  3584
#define CWiv  4096
#define CWps  4608
#define CWpv  5120
#define CWss  5632
#define CWsv  10752
#define NCHUNK_TOT 15872     // 2560 + 6*512 + 2*5120

__device__ __forceinline__ float bitsf(unsigned u){ union{unsigned u; float f;} x; x.u=u; return x.f; }
__device__ __forceinline__ float b2f(unsigned short u){ return bitsf(((unsigned)u)<<16); }
__device__ __forceinline__ unsigned short f2b(float f){
    union{float f; unsigned u;} x; x.f=f;
    unsigned r = x.u + 0x7fffu + ((x.u>>16)&1u);   // RNE
    return (unsigned short)(r>>16);
}
__device__ __forceinline__ short8 pack8(const float* f){
    short8 r;
    #pragma unroll
    for (int j=0;j<8;++j) r[j] = (short)f2b(f[j]);
    return r;
}

__constant__ float kINV_SQRT3 = 0.5773502691896258f;
__constant__ float kINV_SQRT2 = 0.7071067811865476f;
__constant__ float kINV_AVG   = 0.25f;             // 1/sqrt(16)

// ---- merged prep: bucketing (block 0) + all weight swizzles (blocks 1..62) --------------
__global__ __launch_bounds__(256) void kprep(
    const int* __restrict__ specie,
    const float* __restrict__ Wr2,
    const float* __restrict__ Wls, const float* __restrict__ Wlv,
    const float* __restrict__ Wis, const float* __restrict__ Wiv,
    const float* __restrict__ Wps, const float* __restrict__ Wpv,
    const float* __restrict__ Wss, const float* __restrict__ Wsv,
    unsigned short* __restrict__ P,
    int* __restrict__ perm, int* __restrict__ tspec)
{
    const int tid = threadIdx.x;
    if (blockIdx.x == 0){
        __shared__ int cnt[10], base[10], ntl[10], cur[10];
        if (tid < 10) cnt[tid] = 0;
        __syncthreads();
        for (int n = tid; n < NNODES; n += 256) atomicAdd(&cnt[specie[n]], 1);
        __syncthreads();
        if (tid == 0){
            int b = 0;
            for (int sp = 0; sp < 10; ++sp){
                base[sp] = b; cur[sp] = b;
                ntl[sp] = (cnt[sp] + 15) >> 4;
                b += ntl[sp] << 4;
            }
        }
        __syncthreads();
        for (int i = tid; i < NTILES*16; i += 256) perm[i] = -1;
        for (int t = tid; t < NTILES; t += 256){
            int sp = 0;
            #pragma unroll
            for (int k = 0; k < 10; ++k)
                if (t >= (base[k] >> 4) && t < (base[k] >> 4) + ntl[k]) sp = k;
            tspec[t] = sp;
        }
        __syncthreads();
        for (int n = tid; n < NNODES; n += 256){
            int slot = atomicAdd(&cur[specie[n]], 1);
            perm[slot] = n;
        }
        return;
    }
    // swizzle blocks: 62 x 256 = 15872 chunks, one each
    const int c = (blockIdx.x - 1)*256 + tid;
    if (c >= NCHUNK_TOT) return;
    unsigned short t[8];
    if (c < 2560){
        const int nt = c >> 7, ks = (c >> 6) & 1, ln = c & 63;
        const int col = nt*16 + (ln & 15);
        const int jb  = ks*32 + ((ln >> 4) & 3)*8;
        #pragma unroll
        for (int jj = 0; jj < 8; ++jj) t[jj] = f2b(Wr2[(jb+jj)*320 + col]);
    } else {
        int c2 = c - 2560;
        const float* src;
        if      (c2 <  512){ src = Wls; }
        else if (c2 < 1024){ src = Wlv; c2 -= 512; }
        else if (c2 < 1536){ src = Wis; c2 -= 1024; }
        else if (c2 < 2048){ src = Wiv; c2 -= 1536; }
        else if (c2 < 2560){ src = Wps; c2 -= 2048; }
        else if (c2 < 3072){ src = Wpv; c2 -= 2560; }
        else if (c2 < 8192){ src = Wss; c2 -= 3072; }
        else               { src = Wsv; c2 -= 8192; }
        const int grp = c2 >> 9, loc = c2 & 511;
        const int nt = loc >> 7, ks = (loc >> 6) & 1, ln = loc & 63;
        const int col  = nt*16 + (ln & 15);
        const int row0 = grp*64 + ks*32 + ((ln>>4)&3)*8;
        #pragma unroll
        for (int jj = 0; jj < 8; ++jj) t[jj] = f2b(src[(row0+jj)*64 + col]);
    }
    unsigned* d = (unsigned*)(P + (size_t)c*8);
    d[0] = (unsigned)t[0] | ((unsigned)t[1]<<16);
    d[1] = (unsigned)t[2] | ((unsigned)t[3]<<16);
    d[2] = (unsigned)t[4] | ((unsigned)t[5]<<16);
    d[3] = (unsigned)t[6] | ((unsigned)t[7]<<16);
}

// ---- Kernel A (MFMA): zero Ah, then packed sv1 = {s1, v1x, v1y, v1z} --------------------
__global__ __launch_bounds__(256) void knodeA2(
    const float* __restrict__ s, const float* __restrict__ v,
    const unsigned short* __restrict__ P,
    unsigned short* __restrict__ sv1,
    float4v* __restrict__ AhZ)
{
    // zero the fp16 accumulator (NNODES*128 dwords = 640000 float4)
    float4v zz = {0.f,0.f,0.f,0.f};
    for (int i = blockIdx.x*256 + threadIdx.x; i < NNODES*32; i += 313*256) AhZ[i] = zz;

    const int w = threadIdx.x >> 6, lane = threadIdx.x & 63;
    const int t = blockIdx.x*4 + w;
    if (t >= 1250) return;
    const int mcol = lane & 15, quad = lane >> 4;
    const int node = t*16 + mcol;
    const short8* PB = (const short8*)P;

    short8 fS[2], fV[3][2];
    #pragma unroll
    for (int ks = 0; ks < 2; ++ks){
        const int k0 = ks*32 + quad*8;
        float ts[8];
        { float4v a = *(const float4v*)&s[node*64 + k0];
          float4v b = *(const float4v*)&s[node*64 + k0 + 4];
          #pragma unroll
          for (int j = 0; j < 4; ++j){ ts[j] = a[j]; ts[4+j] = b[j]; } }
        fS[ks] = pack8(ts);
        float tv[24];
        #pragma unroll
        for (int q = 0; q < 6; ++q){
            float4v x = *(const float4v*)&v[(node*64 + k0)*3 + q*4];
            #pragma unroll
            for (int j = 0; j < 4; ++j) tv[q*4+j] = x[j];
        }
        #pragma unroll
        for (int c = 0; c < 3; ++c){
            float tc[8];
            #pragma unroll
            for (int j = 0; j < 8; ++j) tc[j] = tv[j*3 + c];
            fV[c][ks] = pack8(tc);
        }
    }
    float4v z = {0.f,0.f,0.f,0.f};
    #pragma unroll
    for (int nt = 0; nt < 4; ++nt){
        float4v aS = __builtin_amdgcn_mfma_f32_16x16x32_bf16(fS[0], PB[CWls+(nt*2+0)*64+lane], z, 0,0,0);
        aS = __builtin_amdgcn_mfma_f32_16x16x32_bf16(fS[1], PB[CWls+(nt*2+1)*64+lane], aS, 0,0,0);
        float4v aV[3];
        #pragma unroll
        for (int c = 0; c < 3; ++c){
            aV[c] = __builtin_amdgcn_mfma_f32_16x16x32_bf16(fV[c][0], PB[CWlv+(nt*2+0)*64+lane], z, 0,0,0);
            aV[c] = __builtin_amdgcn_mfma_f32_16x16x32_bf16(fV[c][1], PB[CWlv+(nt*2+1)*64+lane], aV[c], 0,0,0);
        }
        const int g = nt*16 + mcol;
        #pragma unroll
        for (int r = 0; r < 4; ++r){
            const int nr = t*16 + quad*4 + r;
            ushort4v pk = { f2b(aS[r]), f2b(aV[0][r]), f2b(aV[1][r]), f2b(aV[2][r]) };
            *(ushort4v*)&sv1[(size_t)(nr*64 + g)*4] = pk;
        }
    }
}

// ---- Kernel B: layer1 -> MFMA tw-GEMM -> TP -> per-edge packed-fp16 atomics -------------
__global__ __launch_bounds__(256, 3) void kedge2(
    const float* __restrict__ Y1, const float* __restrict__ ef,
    const int* __restrict__ senders, const int* __restrict__ receivers,
    const float* __restrict__ Wr1, const unsigned short* __restrict__ W2s,
    const unsigned short* __restrict__ sv1,
    half2v* __restrict__ Ah)
{
    __shared__ unsigned short hlds[64*72];
    __shared__ unsigned short twlds[64*330];
    const int lane = threadIdx.x & 63;
    const int w    = threadIdx.x >> 6;
    const int ew   = blockIdx.x*64 + w*16;

    float ef0 = ef[ew*8 + lane];
    float ef1 = ef[ew*8 + 64 + lane];
    float w1r[8];
    #pragma unroll
    for (int r = 0; r < 8; ++r) w1r[r] = Wr1[r*64 + lane];
    float yreg  = (lane < 48) ? Y1[ew*3 + lane] : 0.f;
    int sndreg  = (lane < 16) ? senders[ew + lane]   : 0;
    int rcvreg  = (lane < 16) ? receivers[ew + lane] : 0;

    // T14 prefetch: all 16 sender rows (8 B/lane, 512 B/edge coalesced) issued
    // before the silu/MFMA phases; consumed only in the TP loop.
    ushort4v svp[16];
    #pragma unroll
    for (int e16 = 0; e16 < 16; ++e16){
        const int snd = __shfl(sndreg, e16);
        svp[e16] = *(const ushort4v*)&sv1[(size_t)(snd*64 + lane)*4];
    }

    #pragma unroll
    for (int e16 = 0; e16 < 16; ++e16){
        float src = (e16 < 8) ? ef0 : ef1;
        float hj = 0.f;
        #pragma unroll
        for (int r = 0; r < 8; ++r) hj += __shfl(src, (e16&7)*8 + r) * w1r[r];
        hj = hj / (1.f + __expf(-hj));
        hlds[(w*16 + e16)*72 + lane] = f2b(hj);
    }
    __syncthreads();

    short8 a0 = *(const short8*)&hlds[(w*16 + (lane&15))*72 +      (lane>>4)*8];
    short8 a1 = *(const short8*)&hlds[(w*16 + (lane&15))*72 + 32 + (lane>>4)*8];
    float4v acc[20];
    #pragma unroll
    for (int nt = 0; nt < 20; ++nt){
        short8 b0 = *(const short8*)&W2s[((nt*2+0)*64 + lane)*8];
        short8 b1 = *(const short8*)&W2s[((nt*2+1)*64 + lane)*8];
        float4v z = {0.f, 0.f, 0.f, 0.f};
        acc[nt] = __builtin_amdgcn_mfma_f32_16x16x32_bf16(a0, b0, z, 0, 0, 0);
        acc[nt] = __builtin_amdgcn_mfma_f32_16x16x32_bf16(a1, b1, acc[nt], 0, 0, 0);
    }
    #pragma unroll
    for (int nt = 0; nt < 20; ++nt){
        const int col = nt*16 + (lane & 15);
        #pragma unroll
        for (int r = 0; r < 4; ++r){
            const int erow = w*16 + (lane>>4)*4 + r;
            twlds[erow*330 + col] = f2b(acc[nt][r]);
        }
    }

    for (int e16 = 0; e16 < 16; ++e16){
        const int erow = w*16 + e16;
        float tw0 = b2f(twlds[erow*330 +   0 + lane]);
        float tw1 = b2f(twlds[erow*330 +  64 + lane]);
        float tw2 = b2f(twlds[erow*330 + 128 + lane]);
        float tw3 = b2f(twlds[erow*330 + 192 + lane]);
        float tw4 = b2f(twlds[erow*330 + 256 + lane]);
        const int rcv = __shfl(rcvreg, e16);
        float y0 = __shfl(yreg, e16*3+0);
        float y1 = __shfl(yreg, e16*3+1);
        float y2 = __shfl(yreg, e16*3+2);
        const ushort4v q = svp[e16];
        float ss  = b2f(q[0]);
        float vs0 = b2f(q[1]);
        float vs1 = b2f(q[2]);
        float vs2 = b2f(q[3]);
        float dot = vs0*y0 + vs1*y1 + vs2*y2;
        float c0 = vs1*y2 - vs2*y1;
        float c1 = vs2*y0 - vs0*y2;
        float c2 = vs0*y1 - vs1*y0;
        float ms  = tw0*ss + tw1*dot*kINV_SQRT3;
        float t2s = tw2*ss, t4 = tw4*kINV_SQRT2;
        float mv0 = t2s*y0 + tw3*vs0 + t4*c0;
        float mv1 = t2s*y1 + tw3*vs1 + t4*c1;
        float mv2 = t2s*y2 + tw3*vs2 + t4*c2;
        half2v p01 = { (_Float16)ms,  (_Float16)mv0 };
        half2v p23 = { (_Float16)mv1, (_Float16)mv2 };
        __builtin_amdgcn_global_atomic_fadd_v2f16(&Ah[rcv*128 + lane],      p01);
        __builtin_amdgcn_global_atomic_fadd_v2f16(&Ah[rcv*128 + 64 + lane], p23);
    }
}

// ---- Kernel C (MFMA, species-sorted tiles; vectorized gathers) --------------------------
__global__ __launch_bounds__(256) void knodeC2(
    const float* __restrict__ s, const float* __restrict__ v,
    const half2v* __restrict__ Ah,
    const unsigned short* __restrict__ P,
    const int* __restrict__ perm, const int* __restrict__ tspec,
    const float* __restrict__ wps, const float* __restrict__ wpv,
    const float* __restrict__ Wread,
    float* __restrict__ out)
{
    __shared__ unsigned short Bt[4][4][16*72];
    const int w = threadIdx.x >> 6, lane = threadIdx.x & 63;
    const int t = blockIdx.x*4 + w;
    if (t >= NTILES) return;
    const int mcol = lane & 15, quad = lane >> 4;
    const int spec = tspec[t];
    const int nA   = perm[t*16 + mcol];
    const short8* PB = (const short8*)P;
    const int sb = CWss + spec*512, vb = CWsv + spec*512;

    short8 fAs[2], fAv[3][2], fS[2], fV[3][2];
    if (nA >= 0){
        #pragma unroll
        for (int ks = 0; ks < 2; ++ks){
            const int k0 = ks*32 + quad*8;
            half2v pa[8], pb[8];
            *(float4v*)&pa[0] = *(const float4v*)&Ah[nA*128 + k0];
            *(float4v*)&pa[4] = *(const float4v*)&Ah[nA*128 + k0 + 4];
            *(float4v*)&pb[0] = *(const float4v*)&Ah[nA*128 + 64 + k0];
            *(float4v*)&pb[4] = *(const float4v*)&Ah[nA*128 + 64 + k0 + 4];
            float as_[8], a0_[8], a1_[8], a2_[8];
            #pragma unroll
            for (int j = 0; j < 8; ++j){
                as_[j] = (float)pa[j].x; a0_[j] = (float)pa[j].y;
                a1_[j] = (float)pb[j].x; a2_[j] = (float)pb[j].y;
            }
            fAs[ks] = pack8(as_); fAv[0][ks] = pack8(a0_);
            fAv[1][ks] = pack8(a1_); fAv[2][ks] = pack8(a2_);
            float ts[8];
            { float4v a = *(const float4v*)&s[nA*64 + k0];
              float4v b = *(const float4v*)&s[nA*64 + k0 + 4];
              #pragma unroll
              for (int j = 0; j < 4; ++j){ ts[j] = a[j]; ts[4+j] = b[j]; } }
            fS[ks] = pack8(ts);
            float tv[24];
            #pragma unroll
            for (int q = 0; q < 6; ++q){
                float4v x = *(const float4v*)&v[(nA*64 + k0)*3 + q*4];
                #pragma unroll
                for (int j = 0; j < 4; ++j) tv[q*4+j] = x[j];
            }
            #pragma unroll
            for (int c = 0; c < 3; ++c){
                float tc[8];
                #pragma unroll
                for (int j = 0; j < 8; ++j) tc[j] = tv[j*3 + c];
                fV[c][ks] = pack8(tc);
            }
        }
    } else {
        short8 z8 = {};
        #pragma unroll
        for (int ks = 0; ks < 2; ++ks){
            fAs[ks] = z8; fS[ks] = z8;
            #pragma unroll
            for (int c = 0; c < 3; ++c){ fAv[c][ks] = z8; fV[c][ks] = z8; }
        }
    }

    float4v z = {0.f,0.f,0.f,0.f};
    float4v scS[4], scV[3][4];
    #pragma unroll
    for (int nt = 0; nt < 4; ++nt){
        float4v Ais = __builtin_amdgcn_mfma_f32_16x16x32_bf16(fAs[0], PB[CWis+(nt*2+0)*64+lane], z, 0,0,0);
        Ais = __builtin_amdgcn_mfma_f32_16x16x32_bf16(fAs[1], PB[CWis+(nt*2+1)*64+lane], Ais, 0,0,0);
        float4v Aiv[3];
        #pragma unroll
        for (int c = 0; c < 3; ++c){
            Aiv[c] = __builtin_amdgcn_mfma_f32_16x16x32_bf16(fAv[c][0], PB[CWiv+(nt*2+0)*64+lane], z, 0,0,0);
            Aiv[c] = __builtin_amdgcn_mfma_f32_16x16x32_bf16(fAv[c][1], PB[CWiv+(nt*2+1)*64+lane], Aiv[c], 0,0,0);
        }
        scS[nt] = __builtin_amdgcn_mfma_f32_16x16x32_bf16(fS[0], PB[sb+(nt*2+0)*64+lane], z, 0,0,0);
        scS[nt] = __builtin_amdgcn_mfma_f32_16x16x32_bf16(fS[1], PB[sb+(nt*2+1)*64+lane], scS[nt], 0,0,0);
        #pragma unroll
        for (int c = 0; c < 3; ++c){
            scV[c][nt] = __builtin_amdgcn_mfma_f32_16x16x32_bf16(fV[c][0], PB[vb+(nt*2+0)*64+lane], z, 0,0,0);
            scV[c][nt] = __builtin_amdgcn_mfma_f32_16x16x32_bf16(fV[c][1], PB[vb+(nt*2+1)*64+lane], scV[c][nt], 0,0,0);
        }
        const int g = nt*16 + mcol;
        float w0 = wps[spec*320 +   0 + g], w1 = wps[spec*320 +  64 + g];
        float w2 = wps[spec*320 + 128 + g], w3 = wps[spec*320 + 192 + g];
        float w4 = wps[spec*320 + 256 + g];
        float u0 = wpv[spec*256 +   0 + g], u1 = wpv[spec*256 +  64 + g];
        float u2 = wpv[spec*256 + 128 + g], u3 = wpv[spec*256 + 192 + g];
        #pragma unroll
        for (int r = 0; r < 4; ++r){
            float A  = Ais[r]    * kINV_AVG;
            float a0 = Aiv[0][r] * kINV_AVG;
            float a1 = Aiv[1][r] * kINV_AVG;
            float a2 = Aiv[2][r] * kINV_AVG;
            float d   = a0*a0 + a1*a1 + a2*a2;
            float as2 = A*A;
            float Bs  = w0*A + w1*as2 + w2*d + w3*as2*A + w4*A*d;
            float gg  = u0 + u1*A + u2*as2 + u3*d;
            const int row = quad*4 + r;
            Bt[w][0][row*72 + g] = f2b(Bs);
            Bt[w][1][row*72 + g] = f2b(gg*a0);
            Bt[w][2][row*72 + g] = f2b(gg*a1);
            Bt[w][3][row*72 + g] = f2b(gg*a2);
        }
    }

    short8 bS[2], bV[3][2];
    #pragma unroll
    for (int ks = 0; ks < 2; ++ks){
        bS[ks] = *(const short8*)&Bt[w][0][mcol*72 + ks*32 + quad*8];
        #pragma unroll
        for (int c = 0; c < 3; ++c)
            bV[c][ks] = *(const short8*)&Bt[w][1+c][mcol*72 + ks*32 + quad*8];
    }

    float* out_node = out;
    float* out_s    = out + NNODES;
    float* out_v    = out + NNODES + NNODES*64;
    int ndr[4];
    #pragma unroll
    for (int r = 0; r < 4; ++r) ndr[r] = perm[t*16 + quad*4 + r];
    float4v rd = {0.f,0.f,0.f,0.f};
    #pragma unroll
    for (int nt = 0; nt < 4; ++nt){
        float4v oS = scS[nt];
        oS = __builtin_amdgcn_mfma_f32_16x16x32_bf16(bS[0], PB[CWps+(nt*2+0)*64+lane], oS, 0,0,0);
        oS = __builtin_amdgcn_mfma_f32_16x16x32_bf16(bS[1], PB[CWps+(nt*2+1)*64+lane], oS, 0,0,0);
        float4v oV[3];
        #pragma unroll
        for (int c = 0; c < 3; ++c){
            oV[c] = scV[c][nt];
            oV[c] = __builtin_amdgcn_mfma_f32_16x16x32_bf16(bV[c][0], PB[CWpv+(nt*2+0)*64+lane], oV[c], 0,0,0);
            oV[c] = __builtin_amdgcn_mfma_f32_16x16x32_bf16(bV[c][1], PB[CWpv+(nt*2+1)*64+lane], oV[c], 0,0,0);
        }
        const int g = nt*16 + mcol;
        float wr = Wread[g];
        #pragma unroll
        for (int r = 0; r < 4; ++r){
            if (ndr[r] >= 0){
                out_s[ndr[r]*64 + g] = oS[r];
                #pragma unroll
                for (int c = 0; c < 3; ++c) out_v[(ndr[r]*64 + g)*3 + c] = oV[c][r];
            }
            rd[r] += oS[r] * wr;
        }
    }
    #pragma unroll
    for (int off = 1; off < 16; off <<= 1){
        #pragma unroll
        for (int r = 0; r < 4; ++r) rd[r] += __shfl_xor(rd[r], off);
    }
    if (mcol == 0){
        #pragma unroll
        for (int r = 0; r < 4; ++r) if (ndr[r] >= 0) out_node[ndr[r]] = rd[r];
    }
}

extern "C" void kernel_launch(void* const* d_in, const int* in_sizes, int n_in,
                              void* d_out, int out_size, void* d_ws, size_t ws_size,
                              hipStream_t stream)
{
    (void)in_sizes; (void)n_in; (void)out_size; (void)ws_size;
    const float* s    = (const float*)d_in[0];
    const float* v    = (const float*)d_in[1];
    const float* Y1   = (const float*)d_in[2];
    const float* ef   = (const float*)d_in[3];
    const int* specie = (const int*)d_in[4];
    const int* senders   = (const int*)d_in[5];
    const int* receivers = (const int*)d_in[6];
    const float* Wls  = (const float*)d_in[7];
    const float* Wlv  = (const float*)d_in[8];
    const float* Wss  = (const float*)d_in[9];
    const float* Wsv  = (const float*)d_in[10];
    const float* Wr1  = (const float*)d_in[11];
    const float* Wr2  = (const float*)d_in[12];
    const float* Wis  = (const float*)d_in[13];
    const float* Wiv  = (const float*)d_in[14];
    const float* wps  = (const float*)d_in[15];
    const float* wpv  = (const float*)d_in[16];
    const float* Wps  = (const float*)d_in[17];
    const float* Wpv  = (const float*)d_in[18];
    const float* Wrd  = (const float*)d_in[19];

    float* out = (float*)d_out;
    // packed bf16 sender features {s1, v1x, v1y, v1z} per (node, chan): 10.24 MB
    // scratch in d_out (floats [20000, 2,580,000)); consumed by kedge2, then
    // fully overwritten by knodeC2's out_s/out_v writes.
    unsigned short* t_sv = (unsigned short*)(out + NNODES);

    // ws layout:
    //  [0, 253952)            bf16 fragment pool P
    //  [262144, +10.24M)      Ah fp16 accumulator [N][2][64] half2
    //  [10502144, +80640)     perm[20160]
    //  [10582784, +5040)      tspec[1260]
    char* ws = (char*)d_ws;
    unsigned short* P = (unsigned short*)ws;
    half2v* Ah  = (half2v*)(ws + 262144);
    int* perm   = (int*)(ws + 10502144);
    int* tspec  = (int*)(ws + 10582784);

    kprep<<<63, 256, 0, stream>>>(specie, Wr2, Wls, Wlv, Wis, Wiv, Wps, Wpv, Wss, Wsv,
                                  P, perm, tspec);
    knodeA2<<<313, 256, 0, stream>>>(s, v, P, t_sv, (float4v*)Ah);
    kedge2<<<5000, 256, 0, stream>>>(Y1, ef, senders, receivers, Wr1, P + CW2*8, t_sv, Ah);
    knodeC2<<<315, 256, 0, stream>>>(s, v, Ah, P, perm, tspec, wps, wpv, Wrd, out);
}

// Round 4
// 324.047 us; speedup vs baseline: 1.1541x; 1.0175x over previous
//
#include <hip/hip_runtime.h>

// MACE layer, fp32 I/O. N=20000, E=320000, F=64, P=5, R=8, H=64, S=10.
// R12: receiver-sorted edge processing with FP32 flush (determinism fix).
//   Evidence chain: R11 proved kedge2 is atomic-bound (gather prefetch = 0 gain,
//   163 us == R8); R9 proved sorting cuts the atomic stream (127 us, WRITE
//   160->19 MB); R10's failure isolated the bug to fp16 ROUNDING OF RACY
//   PARTIALS at the flush (R9/R10 numerically identical, diverged on the kscat
//   race draw). Fix: Ah is fp32 [N][4][64]; flushes use HW global_atomic_add_f32
//   (inline asm, no CAS fallback). Racy grouping now only induces fp32 reorder
//   noise (~1e-6) instead of fp16 rounding noise (~4e-3 * |A|).
//   NOTE: ws usage grows to ~19.9 MiB (fp32 Ah = 20.48 MB). If ws_size is
//   smaller this faults -> revert to R11.
// Dispatch chain 6 launches:
//   kprep   : species bucketing + weight swizzles + zero ecnt.
//   knodeA2 : zero Ah(fp32) + receiver histogram + packed sv1 = {s1,v1} GEMM.
//   kscan   : vectorized exclusive prefix over ecnt (int4 x20/thread).
//   kscat   : eperm[atomicAdd(cursor[rcv])] = e (receiver-sorted edge ids).
//   kedge2  : MFMA tw-GEMM + TP; register segment-accum; f32-atomic flush on
//             receiver change.
//   knodeC2 : MFMA + species-sorted tiles; reads fp32 Ah.
#define NNODES 20000
#define NEDGES 320000
#define NTILES 1260

typedef __attribute__((ext_vector_type(8))) short short8;    // 8 bf16
typedef __attribute__((ext_vector_type(4))) float float4v;   // 16 B
typedef __attribute__((ext_vector_type(4))) unsigned short ushort4v; // 8 B
typedef __attribute__((ext_vector_type(4))) int int4v;       // 16 B

// fragment-pool chunk offsets (1 chunk = 8 bf16 = 16 B)
#define CW2   0
#define CWls  2560
#define CWlv  3072
#define CWis  3584
#define CWiv  4096
#define CWps  4608
#define CWpv  5120
#define CWss  5632
#define CWsv  10752
#define NCHUNK_TOT 15872     // 2560 + 6*512 + 2*5120

__device__ __forceinline__ float bitsf(unsigned u){ union{unsigned u; float f;} x; x.u=u; return x.f; }
__device__ __forceinline__ float b2f(unsigned short u){ return bitsf(((unsigned)u)<<16); }
__device__ __forceinline__ unsigned short f2b(float f){
    union{float f; unsigned u;} x; x.f=f;
    unsigned r = x.u + 0x7fffu + ((x.u>>16)&1u);   // RNE
    return (unsigned short)(r>>16);
}
__device__ __forceinline__ short8 pack8(const float* f){
    short8 r;
    #pragma unroll
    for (int j=0;j<8;++j) r[j] = (short)f2b(f[j]);
    return r;
}
// HW fp32 global atomic add (no return, no CAS fallback).
__device__ __forceinline__ void atomAddF32(float* p, float v){
    asm volatile("global_atomic_add_f32 %0, %1, off" :: "v"(p), "v"(v) : "memory");
}

__constant__ float kINV_SQRT3 = 0.5773502691896258f;
__constant__ float kINV_SQRT2 = 0.7071067811865476f;
__constant__ float kINV_AVG   = 0.25f;             // 1/sqrt(16)

// ---- merged prep: bucketing (block 0) + all weight swizzles (blocks 1..62) --------------
__global__ __launch_bounds__(256) void kprep(
    const int* __restrict__ specie,
    const float* __restrict__ Wr2,
    const float* __restrict__ Wls, const float* __restrict__ Wlv,
    const float* __restrict__ Wis, const float* __restrict__ Wiv,
    const float* __restrict__ Wps, const float* __restrict__ Wpv,
    const float* __restrict__ Wss, const float* __restrict__ Wsv,
    unsigned short* __restrict__ P,
    int* __restrict__ perm, int* __restrict__ tspec,
    int* __restrict__ ecnt)
{
    const int tid = threadIdx.x;
    // zero the receiver-histogram (consumed by knodeA2's histogram pass)
    for (int i = blockIdx.x*256 + tid; i < NNODES; i += 63*256) ecnt[i] = 0;

    if (blockIdx.x == 0){
        __shared__ int cnt[10], base[10], ntl[10], cur[10];
        if (tid < 10) cnt[tid] = 0;
        __syncthreads();
        for (int n = tid; n < NNODES; n += 256) atomicAdd(&cnt[specie[n]], 1);
        __syncthreads();
        if (tid == 0){
            int b = 0;
            for (int sp = 0; sp < 10; ++sp){
                base[sp] = b; cur[sp] = b;
                ntl[sp] = (cnt[sp] + 15) >> 4;
                b += ntl[sp] << 4;
            }
        }
        __syncthreads();
        for (int i = tid; i < NTILES*16; i += 256) perm[i] = -1;
        for (int t = tid; t < NTILES; t += 256){
            int sp = 0;
            #pragma unroll
            for (int k = 0; k < 10; ++k)
                if (t >= (base[k] >> 4) && t < (base[k] >> 4) + ntl[k]) sp = k;
            tspec[t] = sp;
        }
        __syncthreads();
        for (int n = tid; n < NNODES; n += 256){
            int slot = atomicAdd(&cur[specie[n]], 1);
            perm[slot] = n;
        }
        return;
    }
    // swizzle blocks: 62 x 256 = 15872 chunks, one each
    const int c = (blockIdx.x - 1)*256 + tid;
    if (c >= NCHUNK_TOT) return;
    unsigned short t[8];
    if (c < 2560){
        const int nt = c >> 7, ks = (c >> 6) & 1, ln = c & 63;
        const int col = nt*16 + (ln & 15);
        const int jb  = ks*32 + ((ln >> 4) & 3)*8;
        #pragma unroll
        for (int jj = 0; jj < 8; ++jj) t[jj] = f2b(Wr2[(jb+jj)*320 + col]);
    } else {
        int c2 = c - 2560;
        const float* src;
        if      (c2 <  512){ src = Wls; }
        else if (c2 < 1024){ src = Wlv; c2 -= 512; }
        else if (c2 < 1536){ src = Wis; c2 -= 1024; }
        else if (c2 < 2048){ src = Wiv; c2 -= 1536; }
        else if (c2 < 2560){ src = Wps; c2 -= 2048; }
        else if (c2 < 3072){ src = Wpv; c2 -= 2560; }
        else if (c2 < 8192){ src = Wss; c2 -= 3072; }
        else               { src = Wsv; c2 -= 8192; }
        const int grp = c2 >> 9, loc = c2 & 511;
        const int nt = loc >> 7, ks = (loc >> 6) & 1, ln = loc & 63;
        const int col  = nt*16 + (ln & 15);
        const int row0 = grp*64 + ks*32 + ((ln>>4)&3)*8;
        #pragma unroll
        for (int jj = 0; jj < 8; ++jj) t[jj] = f2b(src[(row0+jj)*64 + col]);
    }
    unsigned* d = (unsigned*)(P + (size_t)c*8);
    d[0] = (unsigned)t[0] | ((unsigned)t[1]<<16);
    d[1] = (unsigned)t[2] | ((unsigned)t[3]<<16);
    d[2] = (unsigned)t[4] | ((unsigned)t[5]<<16);
    d[3] = (unsigned)t[6] | ((unsigned)t[7]<<16);
}

// ---- Kernel A (MFMA): zero fp32 Ah, receiver histogram, packed sv1 = {s1,v1} ------------
__global__ __launch_bounds__(256) void knodeA2(
    const float* __restrict__ s, const float* __restrict__ v,
    const unsigned short* __restrict__ P,
    const int* __restrict__ receivers, int* __restrict__ ecnt,
    unsigned short* __restrict__ sv1,
    float4v* __restrict__ AhZ)
{
    // zero the fp32 accumulator (NNODES*256 floats = NNODES*64 float4)
    float4v zz = {0.f,0.f,0.f,0.f};
    for (int i = blockIdx.x*256 + threadIdx.x; i < NNODES*64; i += 313*256) AhZ[i] = zz;
    // receiver histogram for the edge counting-sort (ecnt zeroed by kprep)
    for (int e = blockIdx.x*256 + threadIdx.x; e < NEDGES; e += 313*256)
        atomicAdd(&ecnt[receivers[e]], 1);

    const int w = threadIdx.x >> 6, lane = threadIdx.x & 63;
    const int t = blockIdx.x*4 + w;
    if (t >= 1250) return;
    const int mcol = lane & 15, quad = lane >> 4;
    const int node = t*16 + mcol;
    const short8* PB = (const short8*)P;

    short8 fS[2], fV[3][2];
    #pragma unroll
    for (int ks = 0; ks < 2; ++ks){
        const int k0 = ks*32 + quad*8;
        float ts[8];
        { float4v a = *(const float4v*)&s[node*64 + k0];
          float4v b = *(const float4v*)&s[node*64 + k0 + 4];
          #pragma unroll
          for (int j = 0; j < 4; ++j){ ts[j] = a[j]; ts[4+j] = b[j]; } }
        fS[ks] = pack8(ts);
        float tv[24];
        #pragma unroll
        for (int q = 0; q < 6; ++q){
            float4v x = *(const float4v*)&v[(node*64 + k0)*3 + q*4];
            #pragma unroll
            for (int j = 0; j < 4; ++j) tv[q*4+j] = x[j];
        }
        #pragma unroll
        for (int c = 0; c < 3; ++c){
            float tc[8];
            #pragma unroll
            for (int j = 0; j < 8; ++j) tc[j] = tv[j*3 + c];
            fV[c][ks] = pack8(tc);
        }
    }
    float4v z = {0.f,0.f,0.f,0.f};
    #pragma unroll
    for (int nt = 0; nt < 4; ++nt){
        float4v aS = __builtin_amdgcn_mfma_f32_16x16x32_bf16(fS[0], PB[CWls+(nt*2+0)*64+lane], z, 0,0,0);
        aS = __builtin_amdgcn_mfma_f32_16x16x32_bf16(fS[1], PB[CWls+(nt*2+1)*64+lane], aS, 0,0,0);
        float4v aV[3];
        #pragma unroll
        for (int c = 0; c < 3; ++c){
            aV[c] = __builtin_amdgcn_mfma_f32_16x16x32_bf16(fV[c][0], PB[CWlv+(nt*2+0)*64+lane], z, 0,0,0);
            aV[c] = __builtin_amdgcn_mfma_f32_16x16x32_bf16(fV[c][1], PB[CWlv+(nt*2+1)*64+lane], aV[c], 0,0,0);
        }
        const int g = nt*16 + mcol;
        #pragma unroll
        for (int r = 0; r < 4; ++r){
            const int nr = t*16 + quad*4 + r;
            ushort4v pk = { f2b(aS[r]), f2b(aV[0][r]), f2b(aV[1][r]), f2b(aV[2][r]) };
            *(ushort4v*)&sv1[(size_t)(nr*64 + g)*4] = pk;
        }
    }
}

// ---- counting-sort step 2: exclusive prefix sum over ecnt (in place -> cursor) ----------
// 20000 ints = 5000 int4; 256 threads x 20 int4 each, fully unrolled/pipelined.
__global__ __launch_bounds__(256) void kscan(int* __restrict__ ecnt)
{
    __shared__ int part[256];
    const int tid = threadIdx.x;
    int4v* e4 = (int4v*)ecnt;
    const int b4 = tid*20;                 // int4 index base
    int4v c[20];
    #pragma unroll
    for (int i = 0; i < 20; ++i){
        int4v zi = {0,0,0,0};
        c[i] = (b4 + i < 5000) ? e4[b4 + i] : zi;
    }
    int sum = 0;
    #pragma unroll
    for (int i = 0; i < 20; ++i) sum += c[i][0] + c[i][1] + c[i][2] + c[i][3];
    part[tid] = sum;
    __syncthreads();
    if (tid == 0){
        int acc = 0;
        #pragma unroll 1
        for (int i = 0; i < 256; ++i){ int t = part[i]; part[i] = acc; acc += t; }
    }
    __syncthreads();
    int run = part[tid];
    #pragma unroll
    for (int i = 0; i < 20; ++i){
        int4v o;
        o[0] = run; run += c[i][0];
        o[1] = run; run += c[i][1];
        o[2] = run; run += c[i][2];
        o[3] = run; run += c[i][3];
        if (b4 + i < 5000) e4[b4 + i] = o;
    }
}

// ---- counting-sort step 3: scatter edge ids into receiver-sorted order ------------------
__global__ __launch_bounds__(256) void kscat(
    const int* __restrict__ receivers, int* __restrict__ ecur, int* __restrict__ eperm)
{
    const int e = blockIdx.x*256 + threadIdx.x;
    if (e >= NEDGES) return;
    const int pos = atomicAdd(&ecur[receivers[e]], 1);
    eperm[pos] = e;
}

// ---- Kernel B: layer1 -> MFMA tw-GEMM -> TP -> segment-accum + f32-atomic flush ---------
__global__ __launch_bounds__(256, 3) void kedge2(
    const float* __restrict__ Y1, const float* __restrict__ ef,
    const int* __restrict__ senders, const int* __restrict__ receivers,
    const float* __restrict__ Wr1, const unsigned short* __restrict__ W2s,
    const unsigned short* __restrict__ sv1,
    const int* __restrict__ eperm,
    float* __restrict__ Ahf)
{
    __shared__ unsigned short hlds[64*72];
    __shared__ unsigned short twlds[64*330];
    const int lane = threadIdx.x & 63;
    const int w    = threadIdx.x >> 6;
    const int ew   = blockIdx.x*64 + w*16;

    // wave's 16 receiver-sorted edge ids live in lanes 0..15
    int epreg = 0;
    if (lane < 16) epreg = eperm[ew + lane];
    // each lane gathers 2 radial feats of edge (lane>>2): 8 feats/edge over 4 lanes
    const int  eme = __shfl(epreg, lane >> 2);
    const float efa = ef[eme*8 + (lane&3)*2];
    const float efb = ef[eme*8 + (lane&3)*2 + 1];

    float y0r = 0.f, y1r = 0.f, y2r = 0.f;
    int   sndreg = 0, rcvreg = 0;
    if (lane < 16){
        y0r = Y1[epreg*3 + 0];
        y1r = Y1[epreg*3 + 1];
        y2r = Y1[epreg*3 + 2];
        sndreg = senders[epreg];
        rcvreg = receivers[epreg];
    }

    // T14 prefetch: all 16 sender rows (8 B/lane, 512 B/edge coalesced) issued
    // before the silu/MFMA phases; consumed only in the TP loop.
    ushort4v svp[16];
    #pragma unroll
    for (int e16 = 0; e16 < 16; ++e16){
        const int snd = __shfl(sndreg, e16);
        svp[e16] = *(const ushort4v*)&sv1[(size_t)(snd*64 + lane)*4];
    }

    float w1r[8];
    #pragma unroll
    for (int r = 0; r < 8; ++r) w1r[r] = Wr1[r*64 + lane];

    #pragma unroll
    for (int e16 = 0; e16 < 16; ++e16){
        float hj = 0.f;
        #pragma unroll
        for (int r = 0; r < 8; ++r)
            hj += __shfl((r&1) ? efb : efa, e16*4 + (r>>1)) * w1r[r];
        hj = hj / (1.f + __expf(-hj));
        hlds[(w*16 + e16)*72 + lane] = f2b(hj);
    }
    __syncthreads();

    short8 a0 = *(const short8*)&hlds[(w*16 + (lane&15))*72 +      (lane>>4)*8];
    short8 a1 = *(const short8*)&hlds[(w*16 + (lane&15))*72 + 32 + (lane>>4)*8];
    float4v acc[20];
    #pragma unroll
    for (int nt = 0; nt < 20; ++nt){
        short8 b0 = *(const short8*)&W2s[((nt*2+0)*64 + lane)*8];
        short8 b1 = *(const short8*)&W2s[((nt*2+1)*64 + lane)*8];
        float4v z = {0.f, 0.f, 0.f, 0.f};
        acc[nt] = __builtin_amdgcn_mfma_f32_16x16x32_bf16(a0, b0, z, 0, 0, 0);
        acc[nt] = __builtin_amdgcn_mfma_f32_16x16x32_bf16(a1, b1, acc[nt], 0, 0, 0);
    }
    #pragma unroll
    for (int nt = 0; nt < 20; ++nt){
        const int col = nt*16 + (lane & 15);
        #pragma unroll
        for (int r = 0; r < 4; ++r){
            const int erow = w*16 + (lane>>4)*4 + r;
            twlds[erow*330 + col] = f2b(acc[nt][r]);
        }
    }

    // edges are receiver-sorted: accumulate in fp32 regs, flush on receiver change.
    // Flush is 4x HW f32 atomics -> racy segment grouping only causes fp32
    // reorder noise (the R10 failure was fp16 rounding of racy partials).
    int   cur = -1;
    float aS = 0.f, aV0 = 0.f, aV1 = 0.f, aV2 = 0.f;
    #pragma unroll
    for (int e16 = 0; e16 < 16; ++e16){
        const int erow = w*16 + e16;
        float tw0 = b2f(twlds[erow*330 +   0 + lane]);
        float tw1 = b2f(twlds[erow*330 +  64 + lane]);
        float tw2 = b2f(twlds[erow*330 + 128 + lane]);
        float tw3 = b2f(twlds[erow*330 + 192 + lane]);
        float tw4 = b2f(twlds[erow*330 + 256 + lane]);
        const int rcv = __shfl(rcvreg, e16);
        float y0 = __shfl(y0r, e16);
        float y1 = __shfl(y1r, e16);
        float y2 = __shfl(y2r, e16);
        const ushort4v q = svp[e16];
        float ss  = b2f(q[0]);
        float vs0 = b2f(q[1]);
        float vs1 = b2f(q[2]);
        float vs2 = b2f(q[3]);
        float dot = vs0*y0 + vs1*y1 + vs2*y2;
        float c0 = vs1*y2 - vs2*y1;
        float c1 = vs2*y0 - vs0*y2;
        float c2 = vs0*y1 - vs1*y0;
        float ms  = tw0*ss + tw1*dot*kINV_SQRT3;
        float t2s = tw2*ss, t4 = tw4*kINV_SQRT2;
        float mv0 = t2s*y0 + tw3*vs0 + t4*c0;
        float mv1 = t2s*y1 + tw3*vs1 + t4*c1;
        float mv2 = t2s*y2 + tw3*vs2 + t4*c2;
        if (rcv != cur){                       // wave-uniform at runtime (sorted)
            if (cur >= 0){
                float* base = &Ahf[(size_t)cur*256 + lane];
                atomAddF32(base,       aS);
                atomAddF32(base + 64,  aV0);
                atomAddF32(base + 128, aV1);
                atomAddF32(base + 192, aV2);
            }
            cur = rcv;
            aS = 0.f; aV0 = 0.f; aV1 = 0.f; aV2 = 0.f;
        }
        aS += ms; aV0 += mv0; aV1 += mv1; aV2 += mv2;
    }
    if (cur >= 0){
        float* base = &Ahf[(size_t)cur*256 + lane];
        atomAddF32(base,       aS);
        atomAddF32(base + 64,  aV0);
        atomAddF32(base + 128, aV1);
        atomAddF32(base + 192, aV2);
    }
}

// ---- Kernel C (MFMA, species-sorted tiles; fp32 Ah reads) -------------------------------
__global__ __launch_bounds__(256) void knodeC2(
    const float* __restrict__ s, const float* __restrict__ v,
    const float* __restrict__ Ahf,
    const unsigned short* __restrict__ P,
    const int* __restrict__ perm, const int* __restrict__ tspec,
    const float* __restrict__ wps, const float* __restrict__ wpv,
    const float* __restrict__ Wread,
    float* __restrict__ out)
{
    __shared__ unsigned short Bt[4][4][16*72];
    const int w = threadIdx.x >> 6, lane = threadIdx.x & 63;
    const int t = blockIdx.x*4 + w;
    if (t >= NTILES) return;
    const int mcol = lane & 15, quad = lane >> 4;
    const int spec = tspec[t];
    const int nA   = perm[t*16 + mcol];
    const short8* PB = (const short8*)P;
    const int sb = CWss + spec*512, vb = CWsv + spec*512;

    short8 fAs[2], fAv[3][2], fS[2], fV[3][2];
    if (nA >= 0){
        #pragma unroll
        for (int ks = 0; ks < 2; ++ks){
            const int k0 = ks*32 + quad*8;
            const float* ab = &Ahf[(size_t)nA*256 + k0];
            float as_[8], a0_[8], a1_[8], a2_[8];
            { float4v x0 = *(const float4v*)&ab[0];
              float4v x1 = *(const float4v*)&ab[4];
              #pragma unroll
              for (int j = 0; j < 4; ++j){ as_[j] = x0[j]; as_[4+j] = x1[j]; } }
            { float4v x0 = *(const float4v*)&ab[64];
              float4v x1 = *(const float4v*)&ab[68];
              #pragma unroll
              for (int j = 0; j < 4; ++j){ a0_[j] = x0[j]; a0_[4+j] = x1[j]; } }
            { float4v x0 = *(const float4v*)&ab[128];
              float4v x1 = *(const float4v*)&ab[132];
              #pragma unroll
              for (int j = 0; j < 4; ++j){ a1_[j] = x0[j]; a1_[4+j] = x1[j]; } }
            { float4v x0 = *(const float4v*)&ab[192];
              float4v x1 = *(const float4v*)&ab[196];
              #pragma unroll
              for (int j = 0; j < 4; ++j){ a2_[j] = x0[j]; a2_[4+j] = x1[j]; } }
            fAs[ks] = pack8(as_); fAv[0][ks] = pack8(a0_);
            fAv[1][ks] = pack8(a1_); fAv[2][ks] = pack8(a2_);
            float ts[8];
            { float4v a = *(const float4v*)&s[nA*64 + k0];
              float4v b = *(const float4v*)&s[nA*64 + k0 + 4];
              #pragma unroll
              for (int j = 0; j < 4; ++j){ ts[j] = a[j]; ts[4+j] = b[j]; } }
            fS[ks] = pack8(ts);
            float tv[24];
            #pragma unroll
            for (int q = 0; q < 6; ++q){
                float4v x = *(const float4v*)&v[(nA*64 + k0)*3 + q*4];
                #pragma unroll
                for (int j = 0; j < 4; ++j) tv[q*4+j] = x[j];
            }
            #pragma unroll
            for (int c = 0; c < 3; ++c){
                float tc[8];
                #pragma unroll
                for (int j = 0; j < 8; ++j) tc[j] = tv[j*3 + c];
                fV[c][ks] = pack8(tc);
            }
        }
    } else {
        short8 z8 = {};
        #pragma unroll
        for (int ks = 0; ks < 2; ++ks){
            fAs[ks] = z8; fS[ks] = z8;
            #pragma unroll
            for (int c = 0; c < 3; ++c){ fAv[c][ks] = z8; fV[c][ks] = z8; }
        }
    }

    float4v z = {0.f,0.f,0.f,0.f};
    float4v scS[4], scV[3][4];
    #pragma unroll
    for (int nt = 0; nt < 4; ++nt){
        float4v Ais = __builtin_amdgcn_mfma_f32_16x16x32_bf16(fAs[0], PB[CWis+(nt*2+0)*64+lane], z, 0,0,0);
        Ais = __builtin_amdgcn_mfma_f32_16x16x32_bf16(fAs[1], PB[CWis+(nt*2+1)*64+lane], Ais, 0,0,0);
        float4v Aiv[3];
        #pragma unroll
        for (int c = 0; c < 3; ++c){
            Aiv[c] = __builtin_amdgcn_mfma_f32_16x16x32_bf16(fAv[c][0], PB[CWiv+(nt*2+0)*64+lane], z, 0,0,0);
            Aiv[c] = __builtin_amdgcn_mfma_f32_16x16x32_bf16(fAv[c][1], PB[CWiv+(nt*2+1)*64+lane], Aiv[c], 0,0,0);
        }
        scS[nt] = __builtin_amdgcn_mfma_f32_16x16x32_bf16(fS[0], PB[sb+(nt*2+0)*64+lane], z, 0,0,0);
        scS[nt] = __builtin_amdgcn_mfma_f32_16x16x32_bf16(fS[1], PB[sb+(nt*2+1)*64+lane], scS[nt], 0,0,0);
        #pragma unroll
        for (int c = 0; c < 3; ++c){
            scV[c][nt] = __builtin_amdgcn_mfma_f32_16x16x32_bf16(fV[c][0], PB[vb+(nt*2+0)*64+lane], z, 0,0,0);
            scV[c][nt] = __builtin_amdgcn_mfma_f32_16x16x32_bf16(fV[c][1], PB[vb+(nt*2+1)*64+lane], scV[c][nt], 0,0,0);
        }
        const int g = nt*16 + mcol;
        float w0 = wps[spec*320 +   0 + g], w1 = wps[spec*320 +  64 + g];
        float w2 = wps[spec*320 + 128 + g], w3 = wps[spec*320 + 192 + g];
        float w4 = wps[spec*320 + 256 + g];
        float u0 = wpv[spec*256 +   0 + g], u1 = wpv[spec*256 +  64 + g];
        float u2 = wpv[spec*256 + 128 + g], u3 = wpv[spec*256 + 192 + g];
        #pragma unroll
        for (int r = 0; r < 4; ++r){
            float A  = Ais[r]    * kINV_AVG;
            float a0 = Aiv[0][r] * kINV_AVG;
            float a1 = Aiv[1][r] * kINV_AVG;
            float a2 = Aiv[2][r] * kINV_AVG;
            float d   = a0*a0 + a1*a1 + a2*a2;
            float as2 = A*A;
            float Bs  = w0*A + w1*as2 + w2*d + w3*as2*A + w4*A*d;
            float gg  = u0 + u1*A + u2*as2 + u3*d;
            const int row = quad*4 + r;
            Bt[w][0][row*72 + g] = f2b(Bs);
            Bt[w][1][row*72 + g] = f2b(gg*a0);
            Bt[w][2][row*72 + g] = f2b(gg*a1);
            Bt[w][3][row*72 + g] = f2b(gg*a2);
        }
    }

    short8 bS[2], bV[3][2];
    #pragma unroll
    for (int ks = 0; ks < 2; ++ks){
        bS[ks] = *(const short8*)&Bt[w][0][mcol*72 + ks*32 + quad*8];
        #pragma unroll
        for (int c = 0; c < 3; ++c)
            bV[c][ks] = *(const short8*)&Bt[w][1+c][mcol*72 + ks*32 + quad*8];
    }

    float* out_node = out;
    float* out_s    = out + NNODES;
    float* out_v    = out + NNODES + NNODES*64;
    int ndr[4];
    #pragma unroll
    for (int r = 0; r < 4; ++r) ndr[r] = perm[t*16 + quad*4 + r];
    float4v rd = {0.f,0.f,0.f,0.f};
    #pragma unroll
    for (int nt = 0; nt < 4; ++nt){
        float4v oS = scS[nt];
        oS = __builtin_amdgcn_mfma_f32_16x16x32_bf16(bS[0], PB[CWps+(nt*2+0)*64+lane], oS, 0,0,0);
        oS = __builtin_amdgcn_mfma_f32_16x16x32_bf16(bS[1], PB[CWps+(nt*2+1)*64+lane], oS, 0,0,0);
        float4v oV[3];
        #pragma unroll
        for (int c = 0; c < 3; ++c){
            oV[c] = scV[c][nt];
            oV[c] = __builtin_amdgcn_mfma_f32_16x16x32_bf16(bV[c][0], PB[CWpv+(nt*2+0)*64+lane], oV[c], 0,0,0);
            oV[c] = __builtin_amdgcn_mfma_f32_16x16x32_bf16(bV[c][1], PB[CWpv+(nt*2+1)*64+lane], oV[c], 0,0,0);
        }
        const int g = nt*16 + mcol;
        float wr = Wread[g];
        #pragma unroll
        for (int r = 0; r < 4; ++r){
            if (ndr[r] >= 0){
                out_s[ndr[r]*64 + g] = oS[r];
                #pragma unroll
                for (int c = 0; c < 3; ++c) out_v[(ndr[r]*64 + g)*3 + c] = oV[c][r];
            }
            rd[r] += oS[r] * wr;
        }
    }
    #pragma unroll
    for (int off = 1; off < 16; off <<= 1){
        #pragma unroll
        for (int r = 0; r < 4; ++r) rd[r] += __shfl_xor(rd[r], off);
    }
    if (mcol == 0){
        #pragma unroll
        for (int r = 0; r < 4; ++r) if (ndr[r] >= 0) out_node[ndr[r]] = rd[r];
    }
}

extern "C" void kernel_launch(void* const* d_in, const int* in_sizes, int n_in,
                              void* d_out, int out_size, void* d_ws, size_t ws_size,
                              hipStream_t stream)
{
    (void)in_sizes; (void)n_in; (void)out_size; (void)ws_size;
    const float* s    = (const float*)d_in[0];
    const float* v    = (const float*)d_in[1];
    const float* Y1   = (const float*)d_in[2];
    const float* ef   = (const float*)d_in[3];
    const int* specie = (const int*)d_in[4];
    const int* senders   = (const int*)d_in[5];
    const int* receivers = (const int*)d_in[6];
    const float* Wls  = (const float*)d_in[7];
    const float* Wlv  = (const float*)d_in[8];
    const float* Wss  = (const float*)d_in[9];
    const float* Wsv  = (const float*)d_in[10];
    const float* Wr1  = (const float*)d_in[11];
    const float* Wr2  = (const float*)d_in[12];
    const float* Wis  = (const float*)d_in[13];
    const float* Wiv  = (const float*)d_in[14];
    const float* wps  = (const float*)d_in[15];
    const float* wpv  = (const float*)d_in[16];
    const float* Wps  = (const float*)d_in[17];
    const float* Wpv  = (const float*)d_in[18];
    const float* Wrd  = (const float*)d_in[19];

    float* out = (float*)d_out;
    // packed bf16 sender features {s1, v1x, v1y, v1z} per (node, chan): 10.24 MB.
    // Scratch in d_out floats [20000, 2,580,000): consumed by kedge2, then
    // overwritten by knodeC2's out_s/out_v writes (kedge2 completes first).
    unsigned short* t_sv = (unsigned short*)(out + NNODES);
    // counting-sort scratch in the d_out tail (floats [2.60M, 2.95M)); consumed
    // strictly before knodeC2 writes out_v over this range.
    int* ecnt  = (int*)(out + 2600000);    // 20000 ints  (histogram -> cursor)
    int* eperm = (int*)(out + 2624000);    // 320000 ints (receiver-sorted edge ids)

    // ws layout (total 20,827,824 B ~= 19.9 MiB):
    //  [0, 253952)              bf16 fragment pool P
    //  [262144, 20742144)       Ah fp32 accumulator [N][4][64]
    //  [20742144, +80640)       perm[20160]
    //  [20822784, +5040)        tspec[1260]
    char* ws = (char*)d_ws;
    unsigned short* P = (unsigned short*)ws;
    float* Ahf  = (float*)(ws + 262144);
    int* perm   = (int*)(ws + 20742144);
    int* tspec  = (int*)(ws + 20822784);

    kprep<<<63, 256, 0, stream>>>(specie, Wr2, Wls, Wlv, Wis, Wiv, Wps, Wpv, Wss, Wsv,
                                  P, perm, tspec, ecnt);
    knodeA2<<<313, 256, 0, stream>>>(s, v, P, receivers, ecnt, t_sv, (float4v*)Ahf);
    kscan<<<1, 256, 0, stream>>>(ecnt);
    kscat<<<1250, 256, 0, stream>>>(receivers, ecnt, eperm);
    kedge2<<<5000, 256, 0, stream>>>(Y1, ef, senders, receivers, Wr1, P + CW2*8, t_sv, eperm, Ahf);
    knodeC2<<<315, 256, 0, stream>>>(s, v, Ahf, P, perm, tspec, wps, wpv, Wrd, out);
}

// Round 5
// 320.874 us; speedup vs baseline: 1.1655x; 1.0099x over previous
//
#include <hip/hip_runtime.h>

// MACE layer, fp32 I/O. N=20000, E=320000, F=64, P=5, R=8, H=64, S=10.
// R13 = R12 (receiver-sorted + fp32 atomic flush; kedge2 106 us, total 324 us)
//   + fragment reuse: knodeA2 stores its raw-input bf16 fragments (fS/fV) to
//     s_bf[N][64] / v_bf[N][3][64]; knodeC2 loads them as single short8's
//     instead of re-reading fp32 s/v (20.5 MB) and re-packing (~128 f2b
//     VALU ops/thread). Bit-identical transform -> absmax unchanged.
//   ws grows to ~29.6 MiB (R12 proved >=20.8 MiB OK). If ws_size is smaller
//   this faults -> revert to R12.
// Dispatch chain 6 launches:
//   kprep   : species bucketing + weight swizzles + zero ecnt.
//   knodeA2 : zero Ah(fp32) + receiver histogram + packed sv1 GEMM + s_bf/v_bf.
//   kscan   : vectorized exclusive prefix over ecnt.
//   kscat   : eperm[atomicAdd(cursor[rcv])] = e.
//   kedge2  : MFMA tw-GEMM + TP; register segment-accum; f32-atomic flush.
//   knodeC2 : MFMA + species-sorted tiles; fragment loads from s_bf/v_bf.
#define NNODES 20000
#define NEDGES 320000
#define NTILES 1260

typedef __attribute__((ext_vector_type(8))) short short8;    // 8 bf16
typedef __attribute__((ext_vector_type(4))) float float4v;   // 16 B
typedef __attribute__((ext_vector_type(4))) unsigned short ushort4v; // 8 B
typedef __attribute__((ext_vector_type(4))) int int4v;       // 16 B

// fragment-pool chunk offsets (1 chunk = 8 bf16 = 16 B)
#define CW2   0
#define CWls  2560
#define CWlv  3072
#define CWis  3584
#define CWiv  4096
#define CWps  4608
#define CWpv  5120
#define CWss  5632
#define CWsv  10752
#define NCHUNK_TOT 15872     // 2560 + 6*512 + 2*5120

__device__ __forceinline__ float bitsf(unsigned u){ union{unsigned u; float f;} x; x.u=u; return x.f; }
__device__ __forceinline__ float b2f(unsigned short u){ return bitsf(((unsigned)u)<<16); }
__device__ __forceinline__ unsigned short f2b(float f){
    union{float f; unsigned u;} x; x.f=f;
    unsigned r = x.u + 0x7fffu + ((x.u>>16)&1u);   // RNE
    return (unsigned short)(r>>16);
}
__device__ __forceinline__ short8 pack8(const float* f){
    short8 r;
    #pragma unroll
    for (int j=0;j<8;++j) r[j] = (short)f2b(f[j]);
    return r;
}
// HW fp32 global atomic add (no return, no CAS fallback).
__device__ __forceinline__ void atomAddF32(float* p, float v){
    asm volatile("global_atomic_add_f32 %0, %1, off" :: "v"(p), "v"(v) : "memory");
}

__constant__ float kINV_SQRT3 = 0.5773502691896258f;
__constant__ float kINV_SQRT2 = 0.7071067811865476f;
__constant__ float kINV_AVG   = 0.25f;             // 1/sqrt(16)

// ---- merged prep: bucketing (block 0) + all weight swizzles (blocks 1..62) --------------
__global__ __launch_bounds__(256) void kprep(
    const int* __restrict__ specie,
    const float* __restrict__ Wr2,
    const float* __restrict__ Wls, const float* __restrict__ Wlv,
    const float* __restrict__ Wis, const float* __restrict__ Wiv,
    const float* __restrict__ Wps, const float* __restrict__ Wpv,
    const float* __restrict__ Wss, const float* __restrict__ Wsv,
    unsigned short* __restrict__ P,
    int* __restrict__ perm, int* __restrict__ tspec,
    int* __restrict__ ecnt)
{
    const int tid = threadIdx.x;
    // zero the receiver-histogram (consumed by knodeA2's histogram pass)
    for (int i = blockIdx.x*256 + tid; i < NNODES; i += 63*256) ecnt[i] = 0;

    if (blockIdx.x == 0){
        __shared__ int cnt[10], base[10], ntl[10], cur[10];
        if (tid < 10) cnt[tid] = 0;
        __syncthreads();
        for (int n = tid; n < NNODES; n += 256) atomicAdd(&cnt[specie[n]], 1);
        __syncthreads();
        if (tid == 0){
            int b = 0;
            for (int sp = 0; sp < 10; ++sp){
                base[sp] = b; cur[sp] = b;
                ntl[sp] = (cnt[sp] + 15) >> 4;
                b += ntl[sp] << 4;
            }
        }
        __syncthreads();
        for (int i = tid; i < NTILES*16; i += 256) perm[i] = -1;
        for (int t = tid; t < NTILES; t += 256){
            int sp = 0;
            #pragma unroll
            for (int k = 0; k < 10; ++k)
                if (t >= (base[k] >> 4) && t < (base[k] >> 4) + ntl[k]) sp = k;
            tspec[t] = sp;
        }
        __syncthreads();
        for (int n = tid; n < NNODES; n += 256){
            int slot = atomicAdd(&cur[specie[n]], 1);
            perm[slot] = n;
        }
        return;
    }
    // swizzle blocks: 62 x 256 = 15872 chunks, one each
    const int c = (blockIdx.x - 1)*256 + tid;
    if (c >= NCHUNK_TOT) return;
    unsigned short t[8];
    if (c < 2560){
        const int nt = c >> 7, ks = (c >> 6) & 1, ln = c & 63;
        const int col = nt*16 + (ln & 15);
        const int jb  = ks*32 + ((ln >> 4) & 3)*8;
        #pragma unroll
        for (int jj = 0; jj < 8; ++jj) t[jj] = f2b(Wr2[(jb+jj)*320 + col]);
    } else {
        int c2 = c - 2560;
        const float* src;
        if      (c2 <  512){ src = Wls; }
        else if (c2 < 1024){ src = Wlv; c2 -= 512; }
        else if (c2 < 1536){ src = Wis; c2 -= 1024; }
        else if (c2 < 2048){ src = Wiv; c2 -= 1536; }
        else if (c2 < 2560){ src = Wps; c2 -= 2048; }
        else if (c2 < 3072){ src = Wpv; c2 -= 2560; }
        else if (c2 < 8192){ src = Wss; c2 -= 3072; }
        else               { src = Wsv; c2 -= 8192; }
        const int grp = c2 >> 9, loc = c2 & 511;
        const int nt = loc >> 7, ks = (loc >> 6) & 1, ln = loc & 63;
        const int col  = nt*16 + (ln & 15);
        const int row0 = grp*64 + ks*32 + ((ln>>4)&3)*8;
        #pragma unroll
        for (int jj = 0; jj < 8; ++jj) t[jj] = f2b(src[(row0+jj)*64 + col]);
    }
    unsigned* d = (unsigned*)(P + (size_t)c*8);
    d[0] = (unsigned)t[0] | ((unsigned)t[1]<<16);
    d[1] = (unsigned)t[2] | ((unsigned)t[3]<<16);
    d[2] = (unsigned)t[4] | ((unsigned)t[5]<<16);
    d[3] = (unsigned)t[6] | ((unsigned)t[7]<<16);
}

// ---- Kernel A (MFMA): zero fp32 Ah, hist, packed sv1, and s_bf/v_bf fragments -----------
__global__ __launch_bounds__(256) void knodeA2(
    const float* __restrict__ s, const float* __restrict__ v,
    const unsigned short* __restrict__ P,
    const int* __restrict__ receivers, int* __restrict__ ecnt,
    unsigned short* __restrict__ sv1,
    unsigned short* __restrict__ s_bf, unsigned short* __restrict__ v_bf,
    float4v* __restrict__ AhZ)
{
    // zero the fp32 accumulator (NNODES*256 floats = NNODES*64 float4)
    float4v zz = {0.f,0.f,0.f,0.f};
    for (int i = blockIdx.x*256 + threadIdx.x; i < NNODES*64; i += 313*256) AhZ[i] = zz;
    // receiver histogram for the edge counting-sort (ecnt zeroed by kprep)
    for (int e = blockIdx.x*256 + threadIdx.x; e < NEDGES; e += 313*256)
        atomicAdd(&ecnt[receivers[e]], 1);

    const int w = threadIdx.x >> 6, lane = threadIdx.x & 63;
    const int t = blockIdx.x*4 + w;
    if (t >= 1250) return;
    const int mcol = lane & 15, quad = lane >> 4;
    const int node = t*16 + mcol;
    const short8* PB = (const short8*)P;

    short8 fS[2], fV[3][2];
    #pragma unroll
    for (int ks = 0; ks < 2; ++ks){
        const int k0 = ks*32 + quad*8;
        float ts[8];
        { float4v a = *(const float4v*)&s[node*64 + k0];
          float4v b = *(const float4v*)&s[node*64 + k0 + 4];
          #pragma unroll
          for (int j = 0; j < 4; ++j){ ts[j] = a[j]; ts[4+j] = b[j]; } }
        fS[ks] = pack8(ts);
        float tv[24];
        #pragma unroll
        for (int q = 0; q < 6; ++q){
            float4v x = *(const float4v*)&v[(node*64 + k0)*3 + q*4];
            #pragma unroll
            for (int j = 0; j < 4; ++j) tv[q*4+j] = x[j];
        }
        #pragma unroll
        for (int c = 0; c < 3; ++c){
            float tc[8];
            #pragma unroll
            for (int j = 0; j < 8; ++j) tc[j] = tv[j*3 + c];
            fV[c][ks] = pack8(tc);
        }
        // persist raw-input fragments for knodeC2 (bit-identical reuse)
        *(short8*)&s_bf[(size_t)node*64 + k0] = fS[ks];
        #pragma unroll
        for (int c = 0; c < 3; ++c)
            *(short8*)&v_bf[((size_t)node*3 + c)*64 + k0] = fV[c][ks];
    }
    float4v z = {0.f,0.f,0.f,0.f};
    #pragma unroll
    for (int nt = 0; nt < 4; ++nt){
        float4v aS = __builtin_amdgcn_mfma_f32_16x16x32_bf16(fS[0], PB[CWls+(nt*2+0)*64+lane], z, 0,0,0);
        aS = __builtin_amdgcn_mfma_f32_16x16x32_bf16(fS[1], PB[CWls+(nt*2+1)*64+lane], aS, 0,0,0);
        float4v aV[3];
        #pragma unroll
        for (int c = 0; c < 3; ++c){
            aV[c] = __builtin_amdgcn_mfma_f32_16x16x32_bf16(fV[c][0], PB[CWlv+(nt*2+0)*64+lane], z, 0,0,0);
            aV[c] = __builtin_amdgcn_mfma_f32_16x16x32_bf16(fV[c][1], PB[CWlv+(nt*2+1)*64+lane], aV[c], 0,0,0);
        }
        const int g = nt*16 + mcol;
        #pragma unroll
        for (int r = 0; r < 4; ++r){
            const int nr = t*16 + quad*4 + r;
            ushort4v pk = { f2b(aS[r]), f2b(aV[0][r]), f2b(aV[1][r]), f2b(aV[2][r]) };
            *(ushort4v*)&sv1[(size_t)(nr*64 + g)*4] = pk;
        }
    }
}

// ---- counting-sort step 2: exclusive prefix sum over ecnt (in place -> cursor) ----------
// 20000 ints = 5000 int4; 256 threads x 20 int4 each, fully unrolled/pipelined.
__global__ __launch_bounds__(256) void kscan(int* __restrict__ ecnt)
{
    __shared__ int part[256];
    const int tid = threadIdx.x;
    int4v* e4 = (int4v*)ecnt;
    const int b4 = tid*20;                 // int4 index base
    int4v c[20];
    #pragma unroll
    for (int i = 0; i < 20; ++i){
        int4v zi = {0,0,0,0};
        c[i] = (b4 + i < 5000) ? e4[b4 + i] : zi;
    }
    int sum = 0;
    #pragma unroll
    for (int i = 0; i < 20; ++i) sum += c[i][0] + c[i][1] + c[i][2] + c[i][3];
    part[tid] = sum;
    __syncthreads();
    if (tid == 0){
        int acc = 0;
        #pragma unroll 1
        for (int i = 0; i < 256; ++i){ int t = part[i]; part[i] = acc; acc += t; }
    }
    __syncthreads();
    int run = part[tid];
    #pragma unroll
    for (int i = 0; i < 20; ++i){
        int4v o;
        o[0] = run; run += c[i][0];
        o[1] = run; run += c[i][1];
        o[2] = run; run += c[i][2];
        o[3] = run; run += c[i][3];
        if (b4 + i < 5000) e4[b4 + i] = o;
    }
}

// ---- counting-sort step 3: scatter edge ids into receiver-sorted order ------------------
__global__ __launch_bounds__(256) void kscat(
    const int* __restrict__ receivers, int* __restrict__ ecur, int* __restrict__ eperm)
{
    const int e = blockIdx.x*256 + threadIdx.x;
    if (e >= NEDGES) return;
    const int pos = atomicAdd(&ecur[receivers[e]], 1);
    eperm[pos] = e;
}

// ---- Kernel B: layer1 -> MFMA tw-GEMM -> TP -> segment-accum + f32-atomic flush ---------
__global__ __launch_bounds__(256, 3) void kedge2(
    const float* __restrict__ Y1, const float* __restrict__ ef,
    const int* __restrict__ senders, const int* __restrict__ receivers,
    const float* __restrict__ Wr1, const unsigned short* __restrict__ W2s,
    const unsigned short* __restrict__ sv1,
    const int* __restrict__ eperm,
    float* __restrict__ Ahf)
{
    __shared__ unsigned short hlds[64*72];
    __shared__ unsigned short twlds[64*330];
    const int lane = threadIdx.x & 63;
    const int w    = threadIdx.x >> 6;
    const int ew   = blockIdx.x*64 + w*16;

    // wave's 16 receiver-sorted edge ids live in lanes 0..15
    int epreg = 0;
    if (lane < 16) epreg = eperm[ew + lane];
    // each lane gathers 2 radial feats of edge (lane>>2): 8 feats/edge over 4 lanes
    const int  eme = __shfl(epreg, lane >> 2);
    const float efa = ef[eme*8 + (lane&3)*2];
    const float efb = ef[eme*8 + (lane&3)*2 + 1];

    float y0r = 0.f, y1r = 0.f, y2r = 0.f;
    int   sndreg = 0, rcvreg = 0;
    if (lane < 16){
        y0r = Y1[epreg*3 + 0];
        y1r = Y1[epreg*3 + 1];
        y2r = Y1[epreg*3 + 2];
        sndreg = senders[epreg];
        rcvreg = receivers[epreg];
    }

    // T14 prefetch: all 16 sender rows (8 B/lane, 512 B/edge coalesced) issued
    // before the silu/MFMA phases; consumed only in the TP loop.
    ushort4v svp[16];
    #pragma unroll
    for (int e16 = 0; e16 < 16; ++e16){
        const int snd = __shfl(sndreg, e16);
        svp[e16] = *(const ushort4v*)&sv1[(size_t)(snd*64 + lane)*4];
    }

    float w1r[8];
    #pragma unroll
    for (int r = 0; r < 8; ++r) w1r[r] = Wr1[r*64 + lane];

    #pragma unroll
    for (int e16 = 0; e16 < 16; ++e16){
        float hj = 0.f;
        #pragma unroll
        for (int r = 0; r < 8; ++r)
            hj += __shfl((r&1) ? efb : efa, e16*4 + (r>>1)) * w1r[r];
        hj = hj / (1.f + __expf(-hj));
        hlds[(w*16 + e16)*72 + lane] = f2b(hj);
    }
    __syncthreads();

    short8 a0 = *(const short8*)&hlds[(w*16 + (lane&15))*72 +      (lane>>4)*8];
    short8 a1 = *(const short8*)&hlds[(w*16 + (lane&15))*72 + 32 + (lane>>4)*8];
    float4v acc[20];
    #pragma unroll
    for (int nt = 0; nt < 20; ++nt){
        short8 b0 = *(const short8*)&W2s[((nt*2+0)*64 + lane)*8];
        short8 b1 = *(const short8*)&W2s[((nt*2+1)*64 + lane)*8];
        float4v z = {0.f, 0.f, 0.f, 0.f};
        acc[nt] = __builtin_amdgcn_mfma_f32_16x16x32_bf16(a0, b0, z, 0, 0, 0);
        acc[nt] = __builtin_amdgcn_mfma_f32_16x16x32_bf16(a1, b1, acc[nt], 0, 0, 0);
    }
    #pragma unroll
    for (int nt = 0; nt < 20; ++nt){
        const int col = nt*16 + (lane & 15);
        #pragma unroll
        for (int r = 0; r < 4; ++r){
            const int erow = w*16 + (lane>>4)*4 + r;
            twlds[erow*330 + col] = f2b(acc[nt][r]);
        }
    }

    // edges are receiver-sorted: accumulate in fp32 regs, flush on receiver change.
    // Flush is 4x HW f32 atomics -> racy segment grouping only causes fp32
    // reorder noise (the R10 failure was fp16 rounding of racy partials).
    int   cur = -1;
    float aS = 0.f, aV0 = 0.f, aV1 = 0.f, aV2 = 0.f;
    #pragma unroll
    for (int e16 = 0; e16 < 16; ++e16){
        const int erow = w*16 + e16;
        float tw0 = b2f(twlds[erow*330 +   0 + lane]);
        float tw1 = b2f(twlds[erow*330 +  64 + lane]);
        float tw2 = b2f(twlds[erow*330 + 128 + lane]);
        float tw3 = b2f(twlds[erow*330 + 192 + lane]);
        float tw4 = b2f(twlds[erow*330 + 256 + lane]);
        const int rcv = __shfl(rcvreg, e16);
        float y0 = __shfl(y0r, e16);
        float y1 = __shfl(y1r, e16);
        float y2 = __shfl(y2r, e16);
        const ushort4v q = svp[e16];
        float ss  = b2f(q[0]);
        float vs0 = b2f(q[1]);
        float vs1 = b2f(q[2]);
        float vs2 = b2f(q[3]);
        float dot = vs0*y0 + vs1*y1 + vs2*y2;
        float c0 = vs1*y2 - vs2*y1;
        float c1 = vs2*y0 - vs0*y2;
        float c2 = vs0*y1 - vs1*y0;
        float ms  = tw0*ss + tw1*dot*kINV_SQRT3;
        float t2s = tw2*ss, t4 = tw4*kINV_SQRT2;
        float mv0 = t2s*y0 + tw3*vs0 + t4*c0;
        float mv1 = t2s*y1 + tw3*vs1 + t4*c1;
        float mv2 = t2s*y2 + tw3*vs2 + t4*c2;
        if (rcv != cur){                       // wave-uniform at runtime (sorted)
            if (cur >= 0){
                float* base = &Ahf[(size_t)cur*256 + lane];
                atomAddF32(base,       aS);
                atomAddF32(base + 64,  aV0);
                atomAddF32(base + 128, aV1);
                atomAddF32(base + 192, aV2);
            }
            cur = rcv;
            aS = 0.f; aV0 = 0.f; aV1 = 0.f; aV2 = 0.f;
        }
        aS += ms; aV0 += mv0; aV1 += mv1; aV2 += mv2;
    }
    if (cur >= 0){
        float* base = &Ahf[(size_t)cur*256 + lane];
        atomAddF32(base,       aS);
        atomAddF32(base + 64,  aV0);
        atomAddF32(base + 128, aV1);
        atomAddF32(base + 192, aV2);
    }
}

// ---- Kernel C (MFMA, species-sorted tiles; fragment loads from s_bf/v_bf) ---------------
__global__ __launch_bounds__(256) void knodeC2(
    const unsigned short* __restrict__ s_bf, const unsigned short* __restrict__ v_bf,
    const float* __restrict__ Ahf,
    const unsigned short* __restrict__ P,
    const int* __restrict__ perm, const int* __restrict__ tspec,
    const float* __restrict__ wps, const float* __restrict__ wpv,
    const float* __restrict__ Wread,
    float* __restrict__ out)
{
    __shared__ unsigned short Bt[4][4][16*72];
    const int w = threadIdx.x >> 6, lane = threadIdx.x & 63;
    const int t = blockIdx.x*4 + w;
    if (t >= NTILES) return;
    const int mcol = lane & 15, quad = lane >> 4;
    const int spec = tspec[t];
    const int nA   = perm[t*16 + mcol];
    const short8* PB = (const short8*)P;
    const int sb = CWss + spec*512, vb = CWsv + spec*512;

    short8 fAs[2], fAv[3][2], fS[2], fV[3][2];
    if (nA >= 0){
        #pragma unroll
        for (int ks = 0; ks < 2; ++ks){
            const int k0 = ks*32 + quad*8;
            const float* ab = &Ahf[(size_t)nA*256 + k0];
            float as_[8], a0_[8], a1_[8], a2_[8];
            { float4v x0 = *(const float4v*)&ab[0];
              float4v x1 = *(const float4v*)&ab[4];
              #pragma unroll
              for (int j = 0; j < 4; ++j){ as_[j] = x0[j]; as_[4+j] = x1[j]; } }
            { float4v x0 = *(const float4v*)&ab[64];
              float4v x1 = *(const float4v*)&ab[68];
              #pragma unroll
              for (int j = 0; j < 4; ++j){ a0_[j] = x0[j]; a0_[4+j] = x1[j]; } }
            { float4v x0 = *(const float4v*)&ab[128];
              float4v x1 = *(const float4v*)&ab[132];
              #pragma unroll
              for (int j = 0; j < 4; ++j){ a1_[j] = x0[j]; a1_[4+j] = x1[j]; } }
            { float4v x0 = *(const float4v*)&ab[192];
              float4v x1 = *(const float4v*)&ab[196];
              #pragma unroll
              for (int j = 0; j < 4; ++j){ a2_[j] = x0[j]; a2_[4+j] = x1[j]; } }
            fAs[ks] = pack8(as_); fAv[0][ks] = pack8(a0_);
            fAv[1][ks] = pack8(a1_); fAv[2][ks] = pack8(a2_);
            // raw-input fragments: direct bf16 loads (produced by knodeA2)
            fS[ks] = *(const short8*)&s_bf[(size_t)nA*64 + k0];
            #pragma unroll
            for (int c = 0; c < 3; ++c)
                fV[c][ks] = *(const short8*)&v_bf[((size_t)nA*3 + c)*64 + k0];
        }
    } else {
        short8 z8 = {};
        #pragma unroll
        for (int ks = 0; ks < 2; ++ks){
            fAs[ks] = z8; fS[ks] = z8;
            #pragma unroll
            for (int c = 0; c < 3; ++c){ fAv[c][ks] = z8; fV[c][ks] = z8; }
        }
    }

    float4v z = {0.f,0.f,0.f,0.f};
    float4v scS[4], scV[3][4];
    #pragma unroll
    for (int nt = 0; nt < 4; ++nt){
        float4v Ais = __builtin_amdgcn_mfma_f32_16x16x32_bf16(fAs[0], PB[CWis+(nt*2+0)*64+lane], z, 0,0,0);
        Ais = __builtin_amdgcn_mfma_f32_16x16x32_bf16(fAs[1], PB[CWis+(nt*2+1)*64+lane], Ais, 0,0,0);
        float4v Aiv[3];
        #pragma unroll
        for (int c = 0; c < 3; ++c){
            Aiv[c] = __builtin_amdgcn_mfma_f32_16x16x32_bf16(fAv[c][0], PB[CWiv+(nt*2+0)*64+lane], z, 0,0,0);
            Aiv[c] = __builtin_amdgcn_mfma_f32_16x16x32_bf16(fAv[c][1], PB[CWiv+(nt*2+1)*64+lane], Aiv[c], 0,0,0);
        }
        scS[nt] = __builtin_amdgcn_mfma_f32_16x16x32_bf16(fS[0], PB[sb+(nt*2+0)*64+lane], z, 0,0,0);
        scS[nt] = __builtin_amdgcn_mfma_f32_16x16x32_bf16(fS[1], PB[sb+(nt*2+1)*64+lane], scS[nt], 0,0,0);
        #pragma unroll
        for (int c = 0; c < 3; ++c){
            scV[c][nt] = __builtin_amdgcn_mfma_f32_16x16x32_bf16(fV[c][0], PB[vb+(nt*2+0)*64+lane], z, 0,0,0);
            scV[c][nt] = __builtin_amdgcn_mfma_f32_16x16x32_bf16(fV[c][1], PB[vb+(nt*2+1)*64+lane], scV[c][nt], 0,0,0);
        }
        const int g = nt*16 + mcol;
        float w0 = wps[spec*320 +   0 + g], w1 = wps[spec*320 +  64 + g];
        float w2 = wps[spec*320 + 128 + g], w3 = wps[spec*320 + 192 + g];
        float w4 = wps[spec*320 + 256 + g];
        float u0 = wpv[spec*256 +   0 + g], u1 = wpv[spec*256 +  64 + g];
        float u2 = wpv[spec*256 + 128 + g], u3 = wpv[spec*256 + 192 + g];
        #pragma unroll
        for (int r = 0; r < 4; ++r){
            float A  = Ais[r]    * kINV_AVG;
            float a0 = Aiv[0][r] * kINV_AVG;
            float a1 = Aiv[1][r] * kINV_AVG;
            float a2 = Aiv[2][r] * kINV_AVG;
            float d   = a0*a0 + a1*a1 + a2*a2;
            float as2 = A*A;
            float Bs  = w0*A + w1*as2 + w2*d + w3*as2*A + w4*A*d;
            float gg  = u0 + u1*A + u2*as2 + u3*d;
            const int row = quad*4 + r;
            Bt[w][0][row*72 + g] = f2b(Bs);
            Bt[w][1][row*72 + g] = f2b(gg*a0);
            Bt[w][2][row*72 + g] = f2b(gg*a1);
            Bt[w][3][row*72 + g] = f2b(gg*a2);
        }
    }

    short8 bS[2], bV[3][2];
    #pragma unroll
    for (int ks = 0; ks < 2; ++ks){
        bS[ks] = *(const short8*)&Bt[w][0][mcol*72 + ks*32 + quad*8];
        #pragma unroll
        for (int c = 0; c < 3; ++c)
            bV[c][ks] = *(const short8*)&Bt[w][1+c][mcol*72 + ks*32 + quad*8];
    }

    float* out_node = out;
    float* out_s    = out + NNODES;
    float* out_v    = out + NNODES + NNODES*64;
    int ndr[4];
    #pragma unroll
    for (int r = 0; r < 4; ++r) ndr[r] = perm[t*16 + quad*4 + r];
    float4v rd = {0.f,0.f,0.f,0.f};
    #pragma unroll
    for (int nt = 0; nt < 4; ++nt){
        float4v oS = scS[nt];
        oS = __builtin_amdgcn_mfma_f32_16x16x32_bf16(bS[0], PB[CWps+(nt*2+0)*64+lane], oS, 0,0,0);
        oS = __builtin_amdgcn_mfma_f32_16x16x32_bf16(bS[1], PB[CWps+(nt*2+1)*64+lane], oS, 0,0,0);
        float4v oV[3];
        #pragma unroll
        for (int c = 0; c < 3; ++c){
            oV[c] = scV[c][nt];
            oV[c] = __builtin_amdgcn_mfma_f32_16x16x32_bf16(bV[c][0], PB[CWpv+(nt*2+0)*64+lane], oV[c], 0,0,0);
            oV[c] = __builtin_amdgcn_mfma_f32_16x16x32_bf16(bV[c][1], PB[CWpv+(nt*2+1)*64+lane], oV[c], 0,0,0);
        }
        const int g = nt*16 + mcol;
        float wr = Wread[g];
        #pragma unroll
        for (int r = 0; r < 4; ++r){
            if (ndr[r] >= 0){
                out_s[ndr[r]*64 + g] = oS[r];
                #pragma unroll
                for (int c = 0; c < 3; ++c) out_v[(ndr[r]*64 + g)*3 + c] = oV[c][r];
            }
            rd[r] += oS[r] * wr;
        }
    }
    #pragma unroll
    for (int off = 1; off < 16; off <<= 1){
        #pragma unroll
        for (int r = 0; r < 4; ++r) rd[r] += __shfl_xor(rd[r], off);
    }
    if (mcol == 0){
        #pragma unroll
        for (int r = 0; r < 4; ++r) if (ndr[r] >= 0) out_node[ndr[r]] = rd[r];
    }
}

extern "C" void kernel_launch(void* const* d_in, const int* in_sizes, int n_in,
                              void* d_out, int out_size, void* d_ws, size_t ws_size,
                              hipStream_t stream)
{
    (void)in_sizes; (void)n_in; (void)out_size; (void)ws_size;
    const float* s    = (const float*)d_in[0];
    const float* v    = (const float*)d_in[1];
    const float* Y1   = (const float*)d_in[2];
    const float* ef   = (const float*)d_in[3];
    const int* specie = (const int*)d_in[4];
    const int* senders   = (const int*)d_in[5];
    const int* receivers = (const int*)d_in[6];
    const float* Wls  = (const float*)d_in[7];
    const float* Wlv  = (const float*)d_in[8];
    const float* Wss  = (const float*)d_in[9];
    const float* Wsv  = (const float*)d_in[10];
    const float* Wr1  = (const float*)d_in[11];
    const float* Wr2  = (const float*)d_in[12];
    const float* Wis  = (const float*)d_in[13];
    const float* Wiv  = (const float*)d_in[14];
    const float* wps  = (const float*)d_in[15];
    const float* wpv  = (const float*)d_in[16];
    const float* Wps  = (const float*)d_in[17];
    const float* Wpv  = (const float*)d_in[18];
    const float* Wrd  = (const float*)d_in[19];

    float* out = (float*)d_out;
    // packed bf16 sender features {s1, v1x, v1y, v1z} per (node, chan): 10.24 MB.
    // Scratch in d_out floats [20000, 2,580,000): consumed by kedge2, then
    // overwritten by knodeC2's out_s/out_v writes (kedge2 completes first).
    unsigned short* t_sv = (unsigned short*)(out + NNODES);
    // counting-sort scratch in the d_out tail (floats [2.60M, 2.95M)); consumed
    // strictly before knodeC2 writes out_v over this range.
    int* ecnt  = (int*)(out + 2600000);    // 20000 ints  (histogram -> cursor)
    int* eperm = (int*)(out + 2624000);    // 320000 ints (receiver-sorted edge ids)

    // ws layout (total 31,067,824 B ~= 29.6 MiB):
    //  [0, 253952)              bf16 fragment pool P
    //  [262144, 20742144)       Ah fp32 accumulator [N][4][64]
    //  [20742144, +80640)       perm[20160]
    //  [20822784, +5040)        tspec[1260]
    //  [20827824, +2560000)     s_bf [N][64] bf16 raw-input fragments
    //  [23387824, +7680000)     v_bf [N][3][64] bf16 raw-input fragments
    char* ws = (char*)d_ws;
    unsigned short* P = (unsigned short*)ws;
    float* Ahf  = (float*)(ws + 262144);
    int* perm   = (int*)(ws + 20742144);
    int* tspec  = (int*)(ws + 20822784);
    unsigned short* s_bf = (unsigned short*)(ws + 20827824);
    unsigned short* v_bf = (unsigned short*)(ws + 23387824);

    kprep<<<63, 256, 0, stream>>>(specie, Wr2, Wls, Wlv, Wis, Wiv, Wps, Wpv, Wss, Wsv,
                                  P, perm, tspec, ecnt);
    knodeA2<<<313, 256, 0, stream>>>(s, v, P, receivers, ecnt, t_sv, s_bf, v_bf, (float4v*)Ahf);
    kscan<<<1, 256, 0, stream>>>(ecnt);
    kscat<<<1250, 256, 0, stream>>>(receivers, ecnt, eperm);
    kedge2<<<5000, 256, 0, stream>>>(Y1, ef, senders, receivers, Wr1, P + CW2*8, t_sv, eperm, Ahf);
    knodeC2<<<315, 256, 0, stream>>>(s_bf, v_bf, Ahf, P, perm, tspec, wps, wpv, Wrd, out);
}

// Round 6
// 318.497 us; speedup vs baseline: 1.1742x; 1.0075x over previous
//
#include <hip/hip_runtime.h>

// MACE layer, fp32 I/O. N=20000, E=320000, F=64, P=5, R=8, H=64, S=10.
// R14 = R13 + de-amplify kedge2's indirect gathers + lighten knodeA2 prologue.
//   - kscat now materializes SORTED edge streams Y1s[E][3], snds[E], rcvs[E]
//     (6.4 MB in free d_out tail). kedge2 reads them as coalesced streams (R8
//     access pattern) instead of 4-12 B random gathers through eperm -> line
//     amplification (~40-60 MB of the 130 MB FETCH) removed. ef stays indirect
//     (32 B row-granular, cheap).
//   - Ah zeroing + ecnt zeroing via hipMemsetAsync (blit) instead of in-kernel
//     loops; receiver histogram moved from knodeA2 into kprep's underloaded
//     swizzle blocks (ecnt pre-zeroed by memset -> no race).
//   - Flush structure unchanged from R12/R13: receiver-sorted segments,
//     fp32 register accum, HW global_atomic_add_f32 flush (deterministic to
//     fp32 reorder noise only; absmax 0.5 on both prior runs).
// Dispatch chain: memset(ecnt) -> memset(Ahf) -> kprep -> knodeA2 -> kscan
//                 -> kscat -> kedge2 -> knodeC2.
#define NNODES 20000
#define NEDGES 320000
#define NTILES 1260

typedef __attribute__((ext_vector_type(8))) short short8;    // 8 bf16
typedef __attribute__((ext_vector_type(4))) float float4v;   // 16 B
typedef __attribute__((ext_vector_type(4))) unsigned short ushort4v; // 8 B
typedef __attribute__((ext_vector_type(4))) int int4v;       // 16 B

// fragment-pool chunk offsets (1 chunk = 8 bf16 = 16 B)
#define CW2   0
#define CWls  2560
#define CWlv  3072
#define CWis  3584
#define CWiv  4096
#define CWps  4608
#define CWpv  5120
#define CWss  5632
#define CWsv  10752
#define NCHUNK_TOT 15872     // 2560 + 6*512 + 2*5120

__device__ __forceinline__ float bitsf(unsigned u){ union{unsigned u; float f;} x; x.u=u; return x.f; }
__device__ __forceinline__ float b2f(unsigned short u){ return bitsf(((unsigned)u)<<16); }
__device__ __forceinline__ unsigned short f2b(float f){
    union{float f; unsigned u;} x; x.f=f;
    unsigned r = x.u + 0x7fffu + ((x.u>>16)&1u);   // RNE
    return (unsigned short)(r>>16);
}
__device__ __forceinline__ short8 pack8(const float* f){
    short8 r;
    #pragma unroll
    for (int j=0;j<8;++j) r[j] = (short)f2b(f[j]);
    return r;
}
// HW fp32 global atomic add (no return, no CAS fallback).
__device__ __forceinline__ void atomAddF32(float* p, float v){
    asm volatile("global_atomic_add_f32 %0, %1, off" :: "v"(p), "v"(v) : "memory");
}

__constant__ float kINV_SQRT3 = 0.5773502691896258f;
__constant__ float kINV_SQRT2 = 0.7071067811865476f;
__constant__ float kINV_AVG   = 0.25f;             // 1/sqrt(16)

// ---- merged prep: bucketing (block 0) + weight swizzles + receiver histogram ------------
__global__ __launch_bounds__(256) void kprep(
    const int* __restrict__ specie,
    const int* __restrict__ receivers,
    const float* __restrict__ Wr2,
    const float* __restrict__ Wls, const float* __restrict__ Wlv,
    const float* __restrict__ Wis, const float* __restrict__ Wiv,
    const float* __restrict__ Wps, const float* __restrict__ Wpv,
    const float* __restrict__ Wss, const float* __restrict__ Wsv,
    unsigned short* __restrict__ P,
    int* __restrict__ perm, int* __restrict__ tspec,
    int* __restrict__ ecnt)
{
    const int tid = threadIdx.x;
    if (blockIdx.x == 0){
        __shared__ int cnt[10], base[10], ntl[10], cur[10];
        if (tid < 10) cnt[tid] = 0;
        __syncthreads();
        for (int n = tid; n < NNODES; n += 256) atomicAdd(&cnt[specie[n]], 1);
        __syncthreads();
        if (tid == 0){
            int b = 0;
            for (int sp = 0; sp < 10; ++sp){
                base[sp] = b; cur[sp] = b;
                ntl[sp] = (cnt[sp] + 15) >> 4;
                b += ntl[sp] << 4;
            }
        }
        __syncthreads();
        for (int i = tid; i < NTILES*16; i += 256) perm[i] = -1;
        for (int t = tid; t < NTILES; t += 256){
            int sp = 0;
            #pragma unroll
            for (int k = 0; k < 10; ++k)
                if (t >= (base[k] >> 4) && t < (base[k] >> 4) + ntl[k]) sp = k;
            tspec[t] = sp;
        }
        __syncthreads();
        for (int n = tid; n < NNODES; n += 256){
            int slot = atomicAdd(&cur[specie[n]], 1);
            perm[slot] = n;
        }
        return;
    }
    // receiver histogram for the edge counting-sort (ecnt zeroed by memset);
    // runs on the underloaded swizzle blocks, overlapping their weight packing.
    for (int e = (blockIdx.x - 1)*256 + tid; e < NEDGES; e += 62*256)
        atomicAdd(&ecnt[receivers[e]], 1);

    // swizzle blocks: 62 x 256 = 15872 chunks, one each
    const int c = (blockIdx.x - 1)*256 + tid;
    if (c >= NCHUNK_TOT) return;
    unsigned short t[8];
    if (c < 2560){
        const int nt = c >> 7, ks = (c >> 6) & 1, ln = c & 63;
        const int col = nt*16 + (ln & 15);
        const int jb  = ks*32 + ((ln >> 4) & 3)*8;
        #pragma unroll
        for (int jj = 0; jj < 8; ++jj) t[jj] = f2b(Wr2[(jb+jj)*320 + col]);
    } else {
        int c2 = c - 2560;
        const float* src;
        if      (c2 <  512){ src = Wls; }
        else if (c2 < 1024){ src = Wlv; c2 -= 512; }
        else if (c2 < 1536){ src = Wis; c2 -= 1024; }
        else if (c2 < 2048){ src = Wiv; c2 -= 1536; }
        else if (c2 < 2560){ src = Wps; c2 -= 2048; }
        else if (c2 < 3072){ src = Wpv; c2 -= 2560; }
        else if (c2 < 8192){ src = Wss; c2 -= 3072; }
        else               { src = Wsv; c2 -= 8192; }
        const int grp = c2 >> 9, loc = c2 & 511;
        const int nt = loc >> 7, ks = (loc >> 6) & 1, ln = loc & 63;
        const int col  = nt*16 + (ln & 15);
        const int row0 = grp*64 + ks*32 + ((ln>>4)&3)*8;
        #pragma unroll
        for (int jj = 0; jj < 8; ++jj) t[jj] = f2b(src[(row0+jj)*64 + col]);
    }
    unsigned* d = (unsigned*)(P + (size_t)c*8);
    d[0] = (unsigned)t[0] | ((unsigned)t[1]<<16);
    d[1] = (unsigned)t[2] | ((unsigned)t[3]<<16);
    d[2] = (unsigned)t[4] | ((unsigned)t[5]<<16);
    d[3] = (unsigned)t[6] | ((unsigned)t[7]<<16);
}

// ---- Kernel A (MFMA): packed sv1 = {s1,v1} GEMM + s_bf/v_bf fragment store --------------
__global__ __launch_bounds__(256) void knodeA2(
    const float* __restrict__ s, const float* __restrict__ v,
    const unsigned short* __restrict__ P,
    unsigned short* __restrict__ sv1,
    unsigned short* __restrict__ s_bf, unsigned short* __restrict__ v_bf)
{
    const int w = threadIdx.x >> 6, lane = threadIdx.x & 63;
    const int t = blockIdx.x*4 + w;
    if (t >= 1250) return;
    const int mcol = lane & 15, quad = lane >> 4;
    const int node = t*16 + mcol;
    const short8* PB = (const short8*)P;

    short8 fS[2], fV[3][2];
    #pragma unroll
    for (int ks = 0; ks < 2; ++ks){
        const int k0 = ks*32 + quad*8;
        float ts[8];
        { float4v a = *(const float4v*)&s[node*64 + k0];
          float4v b = *(const float4v*)&s[node*64 + k0 + 4];
          #pragma unroll
          for (int j = 0; j < 4; ++j){ ts[j] = a[j]; ts[4+j] = b[j]; } }
        fS[ks] = pack8(ts);
        float tv[24];
        #pragma unroll
        for (int q = 0; q < 6; ++q){
            float4v x = *(const float4v*)&v[(node*64 + k0)*3 + q*4];
            #pragma unroll
            for (int j = 0; j < 4; ++j) tv[q*4+j] = x[j];
        }
        #pragma unroll
        for (int c = 0; c < 3; ++c){
            float tc[8];
            #pragma unroll
            for (int j = 0; j < 8; ++j) tc[j] = tv[j*3 + c];
            fV[c][ks] = pack8(tc);
        }
        // persist raw-input fragments for knodeC2 (bit-identical reuse)
        *(short8*)&s_bf[(size_t)node*64 + k0] = fS[ks];
        #pragma unroll
        for (int c = 0; c < 3; ++c)
            *(short8*)&v_bf[((size_t)node*3 + c)*64 + k0] = fV[c][ks];
    }
    float4v z = {0.f,0.f,0.f,0.f};
    #pragma unroll
    for (int nt = 0; nt < 4; ++nt){
        float4v aS = __builtin_amdgcn_mfma_f32_16x16x32_bf16(fS[0], PB[CWls+(nt*2+0)*64+lane], z, 0,0,0);
        aS = __builtin_amdgcn_mfma_f32_16x16x32_bf16(fS[1], PB[CWls+(nt*2+1)*64+lane], aS, 0,0,0);
        float4v aV[3];
        #pragma unroll
        for (int c = 0; c < 3; ++c){
            aV[c] = __builtin_amdgcn_mfma_f32_16x16x32_bf16(fV[c][0], PB[CWlv+(nt*2+0)*64+lane], z, 0,0,0);
            aV[c] = __builtin_amdgcn_mfma_f32_16x16x32_bf16(fV[c][1], PB[CWlv+(nt*2+1)*64+lane], aV[c], 0,0,0);
        }
        const int g = nt*16 + mcol;
        #pragma unroll
        for (int r = 0; r < 4; ++r){
            const int nr = t*16 + quad*4 + r;
            ushort4v pk = { f2b(aS[r]), f2b(aV[0][r]), f2b(aV[1][r]), f2b(aV[2][r]) };
            *(ushort4v*)&sv1[(size_t)(nr*64 + g)*4] = pk;
        }
    }
}

// ---- counting-sort step 2: exclusive prefix sum over ecnt (in place -> cursor) ----------
__global__ __launch_bounds__(256) void kscan(int* __restrict__ ecnt)
{
    __shared__ int part[256];
    const int tid = threadIdx.x;
    int4v* e4 = (int4v*)ecnt;
    const int b4 = tid*20;                 // int4 index base
    int4v c[20];
    #pragma unroll
    for (int i = 0; i < 20; ++i){
        int4v zi = {0,0,0,0};
        c[i] = (b4 + i < 5000) ? e4[b4 + i] : zi;
    }
    int sum = 0;
    #pragma unroll
    for (int i = 0; i < 20; ++i) sum += c[i][0] + c[i][1] + c[i][2] + c[i][3];
    part[tid] = sum;
    __syncthreads();
    if (tid == 0){
        int acc = 0;
        #pragma unroll 1
        for (int i = 0; i < 256; ++i){ int t = part[i]; part[i] = acc; acc += t; }
    }
    __syncthreads();
    int run = part[tid];
    #pragma unroll
    for (int i = 0; i < 20; ++i){
        int4v o;
        o[0] = run; run += c[i][0];
        o[1] = run; run += c[i][1];
        o[2] = run; run += c[i][2];
        o[3] = run; run += c[i][3];
        if (b4 + i < 5000) e4[b4 + i] = o;
    }
}

// ---- counting-sort step 3: scatter edge ids AND sorted edge streams ---------------------
__global__ __launch_bounds__(256) void kscat(
    const int* __restrict__ receivers, const int* __restrict__ senders,
    const float* __restrict__ Y1,
    int* __restrict__ ecur, int* __restrict__ eperm,
    float* __restrict__ Y1s, int* __restrict__ snds, int* __restrict__ rcvs)
{
    const int e = blockIdx.x*256 + threadIdx.x;
    if (e >= NEDGES) return;
    const int r = receivers[e];
    const int pos = atomicAdd(&ecur[r], 1);
    eperm[pos] = e;
    snds[pos]  = senders[e];
    rcvs[pos]  = r;
    Y1s[pos*3 + 0] = Y1[e*3 + 0];
    Y1s[pos*3 + 1] = Y1[e*3 + 1];
    Y1s[pos*3 + 2] = Y1[e*3 + 2];
}

// ---- Kernel B: layer1 -> MFMA tw-GEMM -> TP -> segment-accum + f32-atomic flush ---------
__global__ __launch_bounds__(256, 3) void kedge2(
    const float* __restrict__ ef,
    const float* __restrict__ Wr1, const unsigned short* __restrict__ W2s,
    const unsigned short* __restrict__ sv1,
    const int* __restrict__ eperm,
    const float* __restrict__ Y1s,
    const int* __restrict__ snds, const int* __restrict__ rcvs,
    float* __restrict__ Ahf)
{
    __shared__ unsigned short hlds[64*72];
    __shared__ unsigned short twlds[64*330];
    const int lane = threadIdx.x & 63;
    const int w    = threadIdx.x >> 6;
    const int ew   = blockIdx.x*64 + w*16;

    // only ef remains indirect (32 B row-granular via eperm); Y1/snd/rcv are
    // sorted streams -> coalesced loads, no line amplification.
    int epreg = 0;
    if (lane < 16) epreg = eperm[ew + lane];
    const int  eme = __shfl(epreg, lane >> 2);
    const float efa = ef[eme*8 + (lane&3)*2];
    const float efb = ef[eme*8 + (lane&3)*2 + 1];

    float yreg  = (lane < 48) ? Y1s[ew*3 + lane] : 0.f;
    int sndreg  = (lane < 16) ? snds[ew + lane] : 0;
    int rcvreg  = (lane < 16) ? rcvs[ew + lane] : 0;

    // T14 prefetch: all 16 sender rows (8 B/lane, 512 B/edge coalesced) issued
    // before the silu/MFMA phases; consumed only in the TP loop.
    ushort4v svp[16];
    #pragma unroll
    for (int e16 = 0; e16 < 16; ++e16){
        const int snd = __shfl(sndreg, e16);
        svp[e16] = *(const ushort4v*)&sv1[(size_t)(snd*64 + lane)*4];
    }

    float w1r[8];
    #pragma unroll
    for (int r = 0; r < 8; ++r) w1r[r] = Wr1[r*64 + lane];

    #pragma unroll
    for (int e16 = 0; e16 < 16; ++e16){
        float hj = 0.f;
        #pragma unroll
        for (int r = 0; r < 8; ++r)
            hj += __shfl((r&1) ? efb : efa, e16*4 + (r>>1)) * w1r[r];
        hj = hj / (1.f + __expf(-hj));
        hlds[(w*16 + e16)*72 + lane] = f2b(hj);
    }
    __syncthreads();

    short8 a0 = *(const short8*)&hlds[(w*16 + (lane&15))*72 +      (lane>>4)*8];
    short8 a1 = *(const short8*)&hlds[(w*16 + (lane&15))*72 + 32 + (lane>>4)*8];
    float4v acc[20];
    #pragma unroll
    for (int nt = 0; nt < 20; ++nt){
        short8 b0 = *(const short8*)&W2s[((nt*2+0)*64 + lane)*8];
        short8 b1 = *(const short8*)&W2s[((nt*2+1)*64 + lane)*8];
        float4v z = {0.f, 0.f, 0.f, 0.f};
        acc[nt] = __builtin_amdgcn_mfma_f32_16x16x32_bf16(a0, b0, z, 0, 0, 0);
        acc[nt] = __builtin_amdgcn_mfma_f32_16x16x32_bf16(a1, b1, acc[nt], 0, 0, 0);
    }
    #pragma unroll
    for (int nt = 0; nt < 20; ++nt){
        const int col = nt*16 + (lane & 15);
        #pragma unroll
        for (int r = 0; r < 4; ++r){
            const int erow = w*16 + (lane>>4)*4 + r;
            twlds[erow*330 + col] = f2b(acc[nt][r]);
        }
    }

    // edges are receiver-sorted: accumulate in fp32 regs, flush on receiver change.
    int   cur = -1;
    float aS = 0.f, aV0 = 0.f, aV1 = 0.f, aV2 = 0.f;
    #pragma unroll
    for (int e16 = 0; e16 < 16; ++e16){
        const int erow = w*16 + e16;
        float tw0 = b2f(twlds[erow*330 +   0 + lane]);
        float tw1 = b2f(twlds[erow*330 +  64 + lane]);
        float tw2 = b2f(twlds[erow*330 + 128 + lane]);
        float tw3 = b2f(twlds[erow*330 + 192 + lane]);
        float tw4 = b2f(twlds[erow*330 + 256 + lane]);
        const int rcv = __shfl(rcvreg, e16);
        float y0 = __shfl(yreg, e16*3+0);
        float y1 = __shfl(yreg, e16*3+1);
        float y2 = __shfl(yreg, e16*3+2);
        const ushort4v q = svp[e16];
        float ss  = b2f(q[0]);
        float vs0 = b2f(q[1]);
        float vs1 = b2f(q[2]);
        float vs2 = b2f(q[3]);
        float dot = vs0*y0 + vs1*y1 + vs2*y2;
        float c0 = vs1*y2 - vs2*y1;
        float c1 = vs2*y0 - vs0*y2;
        float c2 = vs0*y1 - vs1*y0;
        float ms  = tw0*ss + tw1*dot*kINV_SQRT3;
        float t2s = tw2*ss, t4 = tw4*kINV_SQRT2;
        float mv0 = t2s*y0 + tw3*vs0 + t4*c0;
        float mv1 = t2s*y1 + tw3*vs1 + t4*c1;
        float mv2 = t2s*y2 + tw3*vs2 + t4*c2;
        if (rcv != cur){                       // wave-uniform at runtime (sorted)
            if (cur >= 0){
                float* base = &Ahf[(size_t)cur*256 + lane];
                atomAddF32(base,       aS);
                atomAddF32(base + 64,  aV0);
                atomAddF32(base + 128, aV1);
                atomAddF32(base + 192, aV2);
            }
            cur = rcv;
            aS = 0.f; aV0 = 0.f; aV1 = 0.f; aV2 = 0.f;
        }
        aS += ms; aV0 += mv0; aV1 += mv1; aV2 += mv2;
    }
    if (cur >= 0){
        float* base = &Ahf[(size_t)cur*256 + lane];
        atomAddF32(base,       aS);
        atomAddF32(base + 64,  aV0);
        atomAddF32(base + 128, aV1);
        atomAddF32(base + 192, aV2);
    }
}

// ---- Kernel C (MFMA, species-sorted tiles; fragment loads from s_bf/v_bf) ---------------
__global__ __launch_bounds__(256) void knodeC2(
    const unsigned short* __restrict__ s_bf, const unsigned short* __restrict__ v_bf,
    const float* __restrict__ Ahf,
    const unsigned short* __restrict__ P,
    const int* __restrict__ perm, const int* __restrict__ tspec,
    const float* __restrict__ wps, const float* __restrict__ wpv,
    const float* __restrict__ Wread,
    float* __restrict__ out)
{
    __shared__ unsigned short Bt[4][4][16*72];
    const int w = threadIdx.x >> 6, lane = threadIdx.x & 63;
    const int t = blockIdx.x*4 + w;
    if (t >= NTILES) return;
    const int mcol = lane & 15, quad = lane >> 4;
    const int spec = tspec[t];
    const int nA   = perm[t*16 + mcol];
    const short8* PB = (const short8*)P;
    const int sb = CWss + spec*512, vb = CWsv + spec*512;

    short8 fAs[2], fAv[3][2], fS[2], fV[3][2];
    if (nA >= 0){
        #pragma unroll
        for (int ks = 0; ks < 2; ++ks){
            const int k0 = ks*32 + quad*8;
            const float* ab = &Ahf[(size_t)nA*256 + k0];
            float as_[8], a0_[8], a1_[8], a2_[8];
            { float4v x0 = *(const float4v*)&ab[0];
              float4v x1 = *(const float4v*)&ab[4];
              #pragma unroll
              for (int j = 0; j < 4; ++j){ as_[j] = x0[j]; as_[4+j] = x1[j]; } }
            { float4v x0 = *(const float4v*)&ab[64];
              float4v x1 = *(const float4v*)&ab[68];
              #pragma unroll
              for (int j = 0; j < 4; ++j){ a0_[j] = x0[j]; a0_[4+j] = x1[j]; } }
            { float4v x0 = *(const float4v*)&ab[128];
              float4v x1 = *(const float4v*)&ab[132];
              #pragma unroll
              for (int j = 0; j < 4; ++j){ a1_[j] = x0[j]; a1_[4+j] = x1[j]; } }
            { float4v x0 = *(const float4v*)&ab[192];
              float4v x1 = *(const float4v*)&ab[196];
              #pragma unroll
              for (int j = 0; j < 4; ++j){ a2_[j] = x0[j]; a2_[4+j] = x1[j]; } }
            fAs[ks] = pack8(as_); fAv[0][ks] = pack8(a0_);
            fAv[1][ks] = pack8(a1_); fAv[2][ks] = pack8(a2_);
            // raw-input fragments: direct bf16 loads (produced by knodeA2)
            fS[ks] = *(const short8*)&s_bf[(size_t)nA*64 + k0];
            #pragma unroll
            for (int c = 0; c < 3; ++c)
                fV[c][ks] = *(const short8*)&v_bf[((size_t)nA*3 + c)*64 + k0];
        }
    } else {
        short8 z8 = {};
        #pragma unroll
        for (int ks = 0; ks < 2; ++ks){
            fAs[ks] = z8; fS[ks] = z8;
            #pragma unroll
            for (int c = 0; c < 3; ++c){ fAv[c][ks] = z8; fV[c][ks] = z8; }
        }
    }

    float4v z = {0.f,0.f,0.f,0.f};
    float4v scS[4], scV[3][4];
    #pragma unroll
    for (int nt = 0; nt < 4; ++nt){
        float4v Ais = __builtin_amdgcn_mfma_f32_16x16x32_bf16(fAs[0], PB[CWis+(nt*2+0)*64+lane], z, 0,0,0);
        Ais = __builtin_amdgcn_mfma_f32_16x16x32_bf16(fAs[1], PB[CWis+(nt*2+1)*64+lane], Ais, 0,0,0);
        float4v Aiv[3];
        #pragma unroll
        for (int c = 0; c < 3; ++c){
            Aiv[c] = __builtin_amdgcn_mfma_f32_16x16x32_bf16(fAv[c][0], PB[CWiv+(nt*2+0)*64+lane], z, 0,0,0);
            Aiv[c] = __builtin_amdgcn_mfma_f32_16x16x32_bf16(fAv[c][1], PB[CWiv+(nt*2+1)*64+lane], Aiv[c], 0,0,0);
        }
        scS[nt] = __builtin_amdgcn_mfma_f32_16x16x32_bf16(fS[0], PB[sb+(nt*2+0)*64+lane], z, 0,0,0);
        scS[nt] = __builtin_amdgcn_mfma_f32_16x16x32_bf16(fS[1], PB[sb+(nt*2+1)*64+lane], scS[nt], 0,0,0);
        #pragma unroll
        for (int c = 0; c < 3; ++c){
            scV[c][nt] = __builtin_amdgcn_mfma_f32_16x16x32_bf16(fV[c][0], PB[vb+(nt*2+0)*64+lane], z, 0,0,0);
            scV[c][nt] = __builtin_amdgcn_mfma_f32_16x16x32_bf16(fV[c][1], PB[vb+(nt*2+1)*64+lane], scV[c][nt], 0,0,0);
        }
        const int g = nt*16 + mcol;
        float w0 = wps[spec*320 +   0 + g], w1 = wps[spec*320 +  64 + g];
        float w2 = wps[spec*320 + 128 + g], w3 = wps[spec*320 + 192 + g];
        float w4 = wps[spec*320 + 256 + g];
        float u0 = wpv[spec*256 +   0 + g], u1 = wpv[spec*256 +  64 + g];
        float u2 = wpv[spec*256 + 128 + g], u3 = wpv[spec*256 + 192 + g];
        #pragma unroll
        for (int r = 0; r < 4; ++r){
            float A  = Ais[r]    * kINV_AVG;
            float a0 = Aiv[0][r] * kINV_AVG;
            float a1 = Aiv[1][r] * kINV_AVG;
            float a2 = Aiv[2][r] * kINV_AVG;
            float d   = a0*a0 + a1*a1 + a2*a2;
            float as2 = A*A;
            float Bs  = w0*A + w1*as2 + w2*d + w3*as2*A + w4*A*d;
            float gg  = u0 + u1*A + u2*as2 + u3*d;
            const int row = quad*4 + r;
            Bt[w][0][row*72 + g] = f2b(Bs);
            Bt[w][1][row*72 + g] = f2b(gg*a0);
            Bt[w][2][row*72 + g] = f2b(gg*a1);
            Bt[w][3][row*72 + g] = f2b(gg*a2);
        }
    }

    short8 bS[2], bV[3][2];
    #pragma unroll
    for (int ks = 0; ks < 2; ++ks){
        bS[ks] = *(const short8*)&Bt[w][0][mcol*72 + ks*32 + quad*8];
        #pragma unroll
        for (int c = 0; c < 3; ++c)
            bV[c][ks] = *(const short8*)&Bt[w][1+c][mcol*72 + ks*32 + quad*8];
    }

    float* out_node = out;
    float* out_s    = out + NNODES;
    float* out_v    = out + NNODES + NNODES*64;
    int ndr[4];
    #pragma unroll
    for (int r = 0; r < 4; ++r) ndr[r] = perm[t*16 + quad*4 + r];
    float4v rd = {0.f,0.f,0.f,0.f};
    #pragma unroll
    for (int nt = 0; nt < 4; ++nt){
        float4v oS = scS[nt];
        oS = __builtin_amdgcn_mfma_f32_16x16x32_bf16(bS[0], PB[CWps+(nt*2+0)*64+lane], oS, 0,0,0);
        oS = __builtin_amdgcn_mfma_f32_16x16x32_bf16(bS[1], PB[CWps+(nt*2+1)*64+lane], oS, 0,0,0);
        float4v oV[3];
        #pragma unroll
        for (int c = 0; c < 3; ++c){
            oV[c] = scV[c][nt];
            oV[c] = __builtin_amdgcn_mfma_f32_16x16x32_bf16(bV[c][0], PB[CWpv+(nt*2+0)*64+lane], oV[c], 0,0,0);
            oV[c] = __builtin_amdgcn_mfma_f32_16x16x32_bf16(bV[c][1], PB[CWpv+(nt*2+1)*64+lane], oV[c], 0,0,0);
        }
        const int g = nt*16 + mcol;
        float wr = Wread[g];
        #pragma unroll
        for (int r = 0; r < 4; ++r){
            if (ndr[r] >= 0){
                out_s[ndr[r]*64 + g] = oS[r];
                #pragma unroll
                for (int c = 0; c < 3; ++c) out_v[(ndr[r]*64 + g)*3 + c] = oV[c][r];
            }
            rd[r] += oS[r] * wr;
        }
    }
    #pragma unroll
    for (int off = 1; off < 16; off <<= 1){
        #pragma unroll
        for (int r = 0; r < 4; ++r) rd[r] += __shfl_xor(rd[r], off);
    }
    if (mcol == 0){
        #pragma unroll
        for (int r = 0; r < 4; ++r) if (ndr[r] >= 0) out_node[ndr[r]] = rd[r];
    }
}

extern "C" void kernel_launch(void* const* d_in, const int* in_sizes, int n_in,
                              void* d_out, int out_size, void* d_ws, size_t ws_size,
                              hipStream_t stream)
{
    (void)in_sizes; (void)n_in; (void)out_size; (void)ws_size;
    const float* s    = (const float*)d_in[0];
    const float* v    = (const float*)d_in[1];
    const float* Y1   = (const float*)d_in[2];
    const float* ef   = (const float*)d_in[3];
    const int* specie = (const int*)d_in[4];
    const int* senders   = (const int*)d_in[5];
    const int* receivers = (const int*)d_in[6];
    const float* Wls  = (const float*)d_in[7];
    const float* Wlv  = (const float*)d_in[8];
    const float* Wss  = (const float*)d_in[9];
    const float* Wsv  = (const float*)d_in[10];
    const float* Wr1  = (const float*)d_in[11];
    const float* Wr2  = (const float*)d_in[12];
    const float* Wis  = (const float*)d_in[13];
    const float* Wiv  = (const float*)d_in[14];
    const float* wps  = (const float*)d_in[15];
    const float* wpv  = (const float*)d_in[16];
    const float* Wps  = (const float*)d_in[17];
    const float* Wpv  = (const float*)d_in[18];
    const float* Wrd  = (const float*)d_in[19];

    float* out = (float*)d_out;
    // d_out scratch (all consumed by kedge2 before knodeC2 overwrites):
    //   t_sv  floats [20000, 2,580,000)   packed bf16 sender feats (10.24 MB)
    //   ecnt  floats [2.60M, 2.62M)       histogram -> cursor (20000 ints)
    //   eperm floats [2.624M, 2.944M)     receiver-sorted edge ids
    //   Y1s   floats [2.944M, 3.904M)     SORTED Y1 streams [E][3]
    //   snds  floats [3.904M, 4.224M)     SORTED senders
    //   rcvs  floats [4.224M, 4.544M)     SORTED receivers   (< 5.14M total)
    unsigned short* t_sv = (unsigned short*)(out + NNODES);
    int*   ecnt  = (int*)(out + 2600000);
    int*   eperm = (int*)(out + 2624000);
    float* Y1s   = (float*)(out + 2944000);
    int*   snds  = (int*)(out + 3904000);
    int*   rcvs  = (int*)(out + 4224000);

    // ws layout (total 31,067,824 B ~= 29.6 MiB, proven OK in R13):
    //  [0, 253952)              bf16 fragment pool P
    //  [262144, 20742144)       Ah fp32 accumulator [N][4][64]
    //  [20742144, +80640)       perm[20160]
    //  [20822784, +5040)        tspec[1260]
    //  [20827824, +2560000)     s_bf [N][64] bf16 raw-input fragments
    //  [23387824, +7680000)     v_bf [N][3][64] bf16 raw-input fragments
    char* ws = (char*)d_ws;
    unsigned short* P = (unsigned short*)ws;
    float* Ahf  = (float*)(ws + 262144);
    int* perm   = (int*)(ws + 20742144);
    int* tspec  = (int*)(ws + 20822784);
    unsigned short* s_bf = (unsigned short*)(ws + 20827824);
    unsigned short* v_bf = (unsigned short*)(ws + 23387824);

    hipMemsetAsync(ecnt, 0, NNODES*sizeof(int), stream);
    hipMemsetAsync(Ahf, 0, (size_t)NNODES*256*sizeof(float), stream);
    kprep<<<63, 256, 0, stream>>>(specie, receivers, Wr2, Wls, Wlv, Wis, Wiv,
                                  Wps, Wpv, Wss, Wsv, P, perm, tspec, ecnt);
    knodeA2<<<313, 256, 0, stream>>>(s, v, P, t_sv, s_bf, v_bf);
    kscan<<<1, 256, 0, stream>>>(ecnt);
    kscat<<<1250, 256, 0, stream>>>(receivers, senders, Y1, ecnt, eperm, Y1s, snds, rcvs);
    kedge2<<<5000, 256, 0, stream>>>(ef, Wr1, P + CW2*8, t_sv, eperm, Y1s, snds, rcvs, Ahf);
    knodeC2<<<315, 256, 0, stream>>>(s_bf, v_bf, Ahf, P, perm, tspec, wps, wpv, Wrd, out);
}

// Round 7
// 313.854 us; speedup vs baseline: 1.1915x; 1.0148x over previous
//
#include <hip/hip_runtime.h>

// MACE layer, fp32 I/O. N=20000, E=320000, F=64, P=5, R=8, H=64, S=10.
// R15 = R14 kedge2 (sorted streams, fp32 flush; 98 us, FETCH 81 MB) with the
// dispatch chain compacted 8 -> 6 and kscat de-amplified:
//   - no memsets: ecnt zeroed in kprep (all blocks), Ahf zeroed + receiver
//     histogram in knodeA2 (both R13-proven safe orderings).
//   - kscat writes ONE interleaved 20 B record esrt[pos]={snd,rcv,y0,y1,y2}
//     (1-2 lines/edge) instead of 4 scattered writes to 4 arrays (4 lines).
//     kedge2 reads it as 5 coalesced dwords on lanes 0..15.
//   Rationale: budget arithmetic shows ~8-10 us per dispatch boundary
//   (R11 4-dispatch vs R14 8-dispatch non-kedge2 delta minus added work).
//   Numerically bit-identical to R14 -> absmax 0.5 expected.
// Dispatch chain 6 launches:
//   kprep -> knodeA2 -> kscan -> kscat -> kedge2 -> knodeC2.
#define NNODES 20000
#define NEDGES 320000
#define NTILES 1260

typedef __attribute__((ext_vector_type(8))) short short8;    // 8 bf16
typedef __attribute__((ext_vector_type(4))) float float4v;   // 16 B
typedef __attribute__((ext_vector_type(4))) unsigned short ushort4v; // 8 B
typedef __attribute__((ext_vector_type(4))) int int4v;       // 16 B

// fragment-pool chunk offsets (1 chunk = 8 bf16 = 16 B)
#define CW2   0
#define CWls  2560
#define CWlv  3072
#define CWis  3584
#define CWiv  4096
#define CWps  4608
#define CWpv  5120
#define CWss  5632
#define CWsv  10752
#define NCHUNK_TOT 15872     // 2560 + 6*512 + 2*5120

__device__ __forceinline__ float bitsf(unsigned u){ union{unsigned u; float f;} x; x.u=u; return x.f; }
__device__ __forceinline__ float b2f(unsigned short u){ return bitsf(((unsigned)u)<<16); }
__device__ __forceinline__ unsigned short f2b(float f){
    union{float f; unsigned u;} x; x.f=f;
    unsigned r = x.u + 0x7fffu + ((x.u>>16)&1u);   // RNE
    return (unsigned short)(r>>16);
}
__device__ __forceinline__ short8 pack8(const float* f){
    short8 r;
    #pragma unroll
    for (int j=0;j<8;++j) r[j] = (short)f2b(f[j]);
    return r;
}
// HW fp32 global atomic add (no return, no CAS fallback).
__device__ __forceinline__ void atomAddF32(float* p, float v){
    asm volatile("global_atomic_add_f32 %0, %1, off" :: "v"(p), "v"(v) : "memory");
}

__constant__ float kINV_SQRT3 = 0.5773502691896258f;
__constant__ float kINV_SQRT2 = 0.7071067811865476f;
__constant__ float kINV_AVG   = 0.25f;             // 1/sqrt(16)

// ---- merged prep: bucketing (block 0) + weight swizzles; all blocks zero ecnt -----------
__global__ __launch_bounds__(256) void kprep(
    const int* __restrict__ specie,
    const float* __restrict__ Wr2,
    const float* __restrict__ Wls, const float* __restrict__ Wlv,
    const float* __restrict__ Wis, const float* __restrict__ Wiv,
    const float* __restrict__ Wps, const float* __restrict__ Wpv,
    const float* __restrict__ Wss, const float* __restrict__ Wsv,
    unsigned short* __restrict__ P,
    int* __restrict__ perm, int* __restrict__ tspec,
    int* __restrict__ ecnt)
{
    const int tid = threadIdx.x;
    // zero the receiver-histogram (knodeA2 histograms it next dispatch)
    for (int i = blockIdx.x*256 + tid; i < NNODES; i += 63*256) ecnt[i] = 0;

    if (blockIdx.x == 0){
        __shared__ int cnt[10], base[10], ntl[10], cur[10];
        if (tid < 10) cnt[tid] = 0;
        __syncthreads();
        for (int n = tid; n < NNODES; n += 256) atomicAdd(&cnt[specie[n]], 1);
        __syncthreads();
        if (tid == 0){
            int b = 0;
            for (int sp = 0; sp < 10; ++sp){
                base[sp] = b; cur[sp] = b;
                ntl[sp] = (cnt[sp] + 15) >> 4;
                b += ntl[sp] << 4;
            }
        }
        __syncthreads();
        for (int i = tid; i < NTILES*16; i += 256) perm[i] = -1;
        for (int t = tid; t < NTILES; t += 256){
            int sp = 0;
            #pragma unroll
            for (int k = 0; k < 10; ++k)
                if (t >= (base[k] >> 4) && t < (base[k] >> 4) + ntl[k]) sp = k;
            tspec[t] = sp;
        }
        __syncthreads();
        for (int n = tid; n < NNODES; n += 256){
            int slot = atomicAdd(&cur[specie[n]], 1);
            perm[slot] = n;
        }
        return;
    }
    // swizzle blocks: 62 x 256 = 15872 chunks, one each
    const int c = (blockIdx.x - 1)*256 + tid;
    if (c >= NCHUNK_TOT) return;
    unsigned short t[8];
    if (c < 2560){
        const int nt = c >> 7, ks = (c >> 6) & 1, ln = c & 63;
        const int col = nt*16 + (ln & 15);
        const int jb  = ks*32 + ((ln >> 4) & 3)*8;
        #pragma unroll
        for (int jj = 0; jj < 8; ++jj) t[jj] = f2b(Wr2[(jb+jj)*320 + col]);
    } else {
        int c2 = c - 2560;
        const float* src;
        if      (c2 <  512){ src = Wls; }
        else if (c2 < 1024){ src = Wlv; c2 -= 512; }
        else if (c2 < 1536){ src = Wis; c2 -= 1024; }
        else if (c2 < 2048){ src = Wiv; c2 -= 1536; }
        else if (c2 < 2560){ src = Wps; c2 -= 2048; }
        else if (c2 < 3072){ src = Wpv; c2 -= 2560; }
        else if (c2 < 8192){ src = Wss; c2 -= 3072; }
        else               { src = Wsv; c2 -= 8192; }
        const int grp = c2 >> 9, loc = c2 & 511;
        const int nt = loc >> 7, ks = (loc >> 6) & 1, ln = loc & 63;
        const int col  = nt*16 + (ln & 15);
        const int row0 = grp*64 + ks*32 + ((ln>>4)&3)*8;
        #pragma unroll
        for (int jj = 0; jj < 8; ++jj) t[jj] = f2b(src[(row0+jj)*64 + col]);
    }
    unsigned* d = (unsigned*)(P + (size_t)c*8);
    d[0] = (unsigned)t[0] | ((unsigned)t[1]<<16);
    d[1] = (unsigned)t[2] | ((unsigned)t[3]<<16);
    d[2] = (unsigned)t[4] | ((unsigned)t[5]<<16);
    d[3] = (unsigned)t[6] | ((unsigned)t[7]<<16);
}

// ---- Kernel A (MFMA): zero fp32 Ah, receiver histogram, packed sv1, s_bf/v_bf -----------
__global__ __launch_bounds__(256) void knodeA2(
    const float* __restrict__ s, const float* __restrict__ v,
    const unsigned short* __restrict__ P,
    const int* __restrict__ receivers, int* __restrict__ ecnt,
    unsigned short* __restrict__ sv1,
    unsigned short* __restrict__ s_bf, unsigned short* __restrict__ v_bf,
    float4v* __restrict__ AhZ)
{
    // zero the fp32 accumulator (NNODES*256 floats = NNODES*64 float4)
    float4v zz = {0.f,0.f,0.f,0.f};
    for (int i = blockIdx.x*256 + threadIdx.x; i < NNODES*64; i += 313*256) AhZ[i] = zz;
    // receiver histogram for the edge counting-sort (ecnt zeroed by kprep)
    for (int e = blockIdx.x*256 + threadIdx.x; e < NEDGES; e += 313*256)
        atomicAdd(&ecnt[receivers[e]], 1);

    const int w = threadIdx.x >> 6, lane = threadIdx.x & 63;
    const int t = blockIdx.x*4 + w;
    if (t >= 1250) return;
    const int mcol = lane & 15, quad = lane >> 4;
    const int node = t*16 + mcol;
    const short8* PB = (const short8*)P;

    short8 fS[2], fV[3][2];
    #pragma unroll
    for (int ks = 0; ks < 2; ++ks){
        const int k0 = ks*32 + quad*8;
        float ts[8];
        { float4v a = *(const float4v*)&s[node*64 + k0];
          float4v b = *(const float4v*)&s[node*64 + k0 + 4];
          #pragma unroll
          for (int j = 0; j < 4; ++j){ ts[j] = a[j]; ts[4+j] = b[j]; } }
        fS[ks] = pack8(ts);
        float tv[24];
        #pragma unroll
        for (int q = 0; q < 6; ++q){
            float4v x = *(const float4v*)&v[(node*64 + k0)*3 + q*4];
            #pragma unroll
            for (int j = 0; j < 4; ++j) tv[q*4+j] = x[j];
        }
        #pragma unroll
        for (int c = 0; c < 3; ++c){
            float tc[8];
            #pragma unroll
            for (int j = 0; j < 8; ++j) tc[j] = tv[j*3 + c];
            fV[c][ks] = pack8(tc);
        }
        // persist raw-input fragments for knodeC2 (bit-identical reuse)
        *(short8*)&s_bf[(size_t)node*64 + k0] = fS[ks];
        #pragma unroll
        for (int c = 0; c < 3; ++c)
            *(short8*)&v_bf[((size_t)node*3 + c)*64 + k0] = fV[c][ks];
    }
    float4v z = {0.f,0.f,0.f,0.f};
    #pragma unroll
    for (int nt = 0; nt < 4; ++nt){
        float4v aS = __builtin_amdgcn_mfma_f32_16x16x32_bf16(fS[0], PB[CWls+(nt*2+0)*64+lane], z, 0,0,0);
        aS = __builtin_amdgcn_mfma_f32_16x16x32_bf16(fS[1], PB[CWls+(nt*2+1)*64+lane], aS, 0,0,0);
        float4v aV[3];
        #pragma unroll
        for (int c = 0; c < 3; ++c){
            aV[c] = __builtin_amdgcn_mfma_f32_16x16x32_bf16(fV[c][0], PB[CWlv+(nt*2+0)*64+lane], z, 0,0,0);
            aV[c] = __builtin_amdgcn_mfma_f32_16x16x32_bf16(fV[c][1], PB[CWlv+(nt*2+1)*64+lane], aV[c], 0,0,0);
        }
        const int g = nt*16 + mcol;
        #pragma unroll
        for (int r = 0; r < 4; ++r){
            const int nr = t*16 + quad*4 + r;
            ushort4v pk = { f2b(aS[r]), f2b(aV[0][r]), f2b(aV[1][r]), f2b(aV[2][r]) };
            *(ushort4v*)&sv1[(size_t)(nr*64 + g)*4] = pk;
        }
    }
}

// ---- counting-sort step 2: exclusive prefix sum over ecnt (in place -> cursor) ----------
__global__ __launch_bounds__(256) void kscan(int* __restrict__ ecnt)
{
    __shared__ int part[256];
    const int tid = threadIdx.x;
    int4v* e4 = (int4v*)ecnt;
    const int b4 = tid*20;                 // int4 index base
    int4v c[20];
    #pragma unroll
    for (int i = 0; i < 20; ++i){
        int4v zi = {0,0,0,0};
        c[i] = (b4 + i < 5000) ? e4[b4 + i] : zi;
    }
    int sum = 0;
    #pragma unroll
    for (int i = 0; i < 20; ++i) sum += c[i][0] + c[i][1] + c[i][2] + c[i][3];
    part[tid] = sum;
    __syncthreads();
    if (tid == 0){
        int acc = 0;
        #pragma unroll 1
        for (int i = 0; i < 256; ++i){ int t = part[i]; part[i] = acc; acc += t; }
    }
    __syncthreads();
    int run = part[tid];
    #pragma unroll
    for (int i = 0; i < 20; ++i){
        int4v o;
        o[0] = run; run += c[i][0];
        o[1] = run; run += c[i][1];
        o[2] = run; run += c[i][2];
        o[3] = run; run += c[i][3];
        if (b4 + i < 5000) e4[b4 + i] = o;
    }
}

// ---- counting-sort step 3: scatter edge ids + interleaved 20 B edge records -------------
__global__ __launch_bounds__(256) void kscat(
    const int* __restrict__ receivers, const int* __restrict__ senders,
    const float* __restrict__ Y1,
    int* __restrict__ ecur, int* __restrict__ eperm, int* __restrict__ esrt)
{
    const int e = blockIdx.x*256 + threadIdx.x;
    if (e >= NEDGES) return;
    const int r = receivers[e];
    const int pos = atomicAdd(&ecur[r], 1);
    eperm[pos] = e;
    int* eb = &esrt[(size_t)pos*5];
    eb[0] = senders[e];
    eb[1] = r;
    eb[2] = __float_as_int(Y1[e*3 + 0]);
    eb[3] = __float_as_int(Y1[e*3 + 1]);
    eb[4] = __float_as_int(Y1[e*3 + 2]);
}

// ---- Kernel B: layer1 -> MFMA tw-GEMM -> TP -> segment-accum + f32-atomic flush ---------
__global__ __launch_bounds__(256, 3) void kedge2(
    const float* __restrict__ ef,
    const float* __restrict__ Wr1, const unsigned short* __restrict__ W2s,
    const unsigned short* __restrict__ sv1,
    const int* __restrict__ eperm, const int* __restrict__ esrt,
    float* __restrict__ Ahf)
{
    __shared__ unsigned short hlds[64*72];
    __shared__ unsigned short twlds[64*330];
    const int lane = threadIdx.x & 63;
    const int w    = threadIdx.x >> 6;
    const int ew   = blockIdx.x*64 + w*16;

    // only ef remains indirect (32 B row-granular via eperm); the per-edge
    // record {snd,rcv,y0,y1,y2} is a sorted coalesced 20 B stream.
    int epreg = 0;
    if (lane < 16) epreg = eperm[ew + lane];
    const int  eme = __shfl(epreg, lane >> 2);
    const float efa = ef[eme*8 + (lane&3)*2];
    const float efb = ef[eme*8 + (lane&3)*2 + 1];

    float y0r = 0.f, y1r = 0.f, y2r = 0.f;
    int   sndreg = 0, rcvreg = 0;
    if (lane < 16){
        const int* eb = &esrt[(size_t)(ew + lane)*5];
        sndreg = eb[0];
        rcvreg = eb[1];
        y0r = __int_as_float(eb[2]);
        y1r = __int_as_float(eb[3]);
        y2r = __int_as_float(eb[4]);
    }

    // T14 prefetch: all 16 sender rows (8 B/lane, 512 B/edge coalesced) issued
    // before the silu/MFMA phases; consumed only in the TP loop.
    ushort4v svp[16];
    #pragma unroll
    for (int e16 = 0; e16 < 16; ++e16){
        const int snd = __shfl(sndreg, e16);
        svp[e16] = *(const ushort4v*)&sv1[(size_t)(snd*64 + lane)*4];
    }

    float w1r[8];
    #pragma unroll
    for (int r = 0; r < 8; ++r) w1r[r] = Wr1[r*64 + lane];

    #pragma unroll
    for (int e16 = 0; e16 < 16; ++e16){
        float hj = 0.f;
        #pragma unroll
        for (int r = 0; r < 8; ++r)
            hj += __shfl((r&1) ? efb : efa, e16*4 + (r>>1)) * w1r[r];
        hj = hj / (1.f + __expf(-hj));
        hlds[(w*16 + e16)*72 + lane] = f2b(hj);
    }
    __syncthreads();

    short8 a0 = *(const short8*)&hlds[(w*16 + (lane&15))*72 +      (lane>>4)*8];
    short8 a1 = *(const short8*)&hlds[(w*16 + (lane&15))*72 + 32 + (lane>>4)*8];
    float4v acc[20];
    #pragma unroll
    for (int nt = 0; nt < 20; ++nt){
        short8 b0 = *(const short8*)&W2s[((nt*2+0)*64 + lane)*8];
        short8 b1 = *(const short8*)&W2s[((nt*2+1)*64 + lane)*8];
        float4v z = {0.f, 0.f, 0.f, 0.f};
        acc[nt] = __builtin_amdgcn_mfma_f32_16x16x32_bf16(a0, b0, z, 0, 0, 0);
        acc[nt] = __builtin_amdgcn_mfma_f32_16x16x32_bf16(a1, b1, acc[nt], 0, 0, 0);
    }
    #pragma unroll
    for (int nt = 0; nt < 20; ++nt){
        const int col = nt*16 + (lane & 15);
        #pragma unroll
        for (int r = 0; r < 4; ++r){
            const int erow = w*16 + (lane>>4)*4 + r;
            twlds[erow*330 + col] = f2b(acc[nt][r]);
        }
    }

    // edges are receiver-sorted: accumulate in fp32 regs, flush on receiver change.
    int   cur = -1;
    float aS = 0.f, aV0 = 0.f, aV1 = 0.f, aV2 = 0.f;
    #pragma unroll
    for (int e16 = 0; e16 < 16; ++e16){
        const int erow = w*16 + e16;
        float tw0 = b2f(twlds[erow*330 +   0 + lane]);
        float tw1 = b2f(twlds[erow*330 +  64 + lane]);
        float tw2 = b2f(twlds[erow*330 + 128 + lane]);
        float tw3 = b2f(twlds[erow*330 + 192 + lane]);
        float tw4 = b2f(twlds[erow*330 + 256 + lane]);
        const int rcv = __shfl(rcvreg, e16);
        float y0 = __shfl(y0r, e16);
        float y1 = __shfl(y1r, e16);
        float y2 = __shfl(y2r, e16);
        const ushort4v q = svp[e16];
        float ss  = b2f(q[0]);
        float vs0 = b2f(q[1]);
        float vs1 = b2f(q[2]);
        float vs2 = b2f(q[3]);
        float dot = vs0*y0 + vs1*y1 + vs2*y2;
        float c0 = vs1*y2 - vs2*y1;
        float c1 = vs2*y0 - vs0*y2;
        float c2 = vs0*y1 - vs1*y0;
        float ms  = tw0*ss + tw1*dot*kINV_SQRT3;
        float t2s = tw2*ss, t4 = tw4*kINV_SQRT2;
        float mv0 = t2s*y0 + tw3*vs0 + t4*c0;
        float mv1 = t2s*y1 + tw3*vs1 + t4*c1;
        float mv2 = t2s*y2 + tw3*vs2 + t4*c2;
        if (rcv != cur){                       // wave-uniform at runtime (sorted)
            if (cur >= 0){
                float* base = &Ahf[(size_t)cur*256 + lane];
                atomAddF32(base,       aS);
                atomAddF32(base + 64,  aV0);
                atomAddF32(base + 128, aV1);
                atomAddF32(base + 192, aV2);
            }
            cur = rcv;
            aS = 0.f; aV0 = 0.f; aV1 = 0.f; aV2 = 0.f;
        }
        aS += ms; aV0 += mv0; aV1 += mv1; aV2 += mv2;
    }
    if (cur >= 0){
        float* base = &Ahf[(size_t)cur*256 + lane];
        atomAddF32(base,       aS);
        atomAddF32(base + 64,  aV0);
        atomAddF32(base + 128, aV1);
        atomAddF32(base + 192, aV2);
    }
}

// ---- Kernel C (MFMA, species-sorted tiles; fragment loads from s_bf/v_bf) ---------------
__global__ __launch_bounds__(256) void knodeC2(
    const unsigned short* __restrict__ s_bf, const unsigned short* __restrict__ v_bf,
    const float* __restrict__ Ahf,
    const unsigned short* __restrict__ P,
    const int* __restrict__ perm, const int* __restrict__ tspec,
    const float* __restrict__ wps, const float* __restrict__ wpv,
    const float* __restrict__ Wread,
    float* __restrict__ out)
{
    __shared__ unsigned short Bt[4][4][16*72];
    const int w = threadIdx.x >> 6, lane = threadIdx.x & 63;
    const int t = blockIdx.x*4 + w;
    if (t >= NTILES) return;
    const int mcol = lane & 15, quad = lane >> 4;
    const int spec = tspec[t];
    const int nA   = perm[t*16 + mcol];
    const short8* PB = (const short8*)P;
    const int sb = CWss + spec*512, vb = CWsv + spec*512;

    short8 fAs[2], fAv[3][2], fS[2], fV[3][2];
    if (nA >= 0){
        #pragma unroll
        for (int ks = 0; ks < 2; ++ks){
            const int k0 = ks*32 + quad*8;
            const float* ab = &Ahf[(size_t)nA*256 + k0];
            float as_[8], a0_[8], a1_[8], a2_[8];
            { float4v x0 = *(const float4v*)&ab[0];
              float4v x1 = *(const float4v*)&ab[4];
              #pragma unroll
              for (int j = 0; j < 4; ++j){ as_[j] = x0[j]; as_[4+j] = x1[j]; } }
            { float4v x0 = *(const float4v*)&ab[64];
              float4v x1 = *(const float4v*)&ab[68];
              #pragma unroll
              for (int j = 0; j < 4; ++j){ a0_[j] = x0[j]; a0_[4+j] = x1[j]; } }
            { float4v x0 = *(const float4v*)&ab[128];
              float4v x1 = *(const float4v*)&ab[132];
              #pragma unroll
              for (int j = 0; j < 4; ++j){ a1_[j] = x0[j]; a1_[4+j] = x1[j]; } }
            { float4v x0 = *(const float4v*)&ab[192];
              float4v x1 = *(const float4v*)&ab[196];
              #pragma unroll
              for (int j = 0; j < 4; ++j){ a2_[j] = x0[j]; a2_[4+j] = x1[j]; } }
            fAs[ks] = pack8(as_); fAv[0][ks] = pack8(a0_);
            fAv[1][ks] = pack8(a1_); fAv[2][ks] = pack8(a2_);
            // raw-input fragments: direct bf16 loads (produced by knodeA2)
            fS[ks] = *(const short8*)&s_bf[(size_t)nA*64 + k0];
            #pragma unroll
            for (int c = 0; c < 3; ++c)
                fV[c][ks] = *(const short8*)&v_bf[((size_t)nA*3 + c)*64 + k0];
        }
    } else {
        short8 z8 = {};
        #pragma unroll
        for (int ks = 0; ks < 2; ++ks){
            fAs[ks] = z8; fS[ks] = z8;
            #pragma unroll
            for (int c = 0; c < 3; ++c){ fAv[c][ks] = z8; fV[c][ks] = z8; }
        }
    }

    float4v z = {0.f,0.f,0.f,0.f};
    float4v scS[4], scV[3][4];
    #pragma unroll
    for (int nt = 0; nt < 4; ++nt){
        float4v Ais = __builtin_amdgcn_mfma_f32_16x16x32_bf16(fAs[0], PB[CWis+(nt*2+0)*64+lane], z, 0,0,0);
        Ais = __builtin_amdgcn_mfma_f32_16x16x32_bf16(fAs[1], PB[CWis+(nt*2+1)*64+lane], Ais, 0,0,0);
        float4v Aiv[3];
        #pragma unroll
        for (int c = 0; c < 3; ++c){
            Aiv[c] = __builtin_amdgcn_mfma_f32_16x16x32_bf16(fAv[c][0], PB[CWiv+(nt*2+0)*64+lane], z, 0,0,0);
            Aiv[c] = __builtin_amdgcn_mfma_f32_16x16x32_bf16(fAv[c][1], PB[CWiv+(nt*2+1)*64+lane], Aiv[c], 0,0,0);
        }
        scS[nt] = __builtin_amdgcn_mfma_f32_16x16x32_bf16(fS[0], PB[sb+(nt*2+0)*64+lane], z, 0,0,0);
        scS[nt] = __builtin_amdgcn_mfma_f32_16x16x32_bf16(fS[1], PB[sb+(nt*2+1)*64+lane], scS[nt], 0,0,0);
        #pragma unroll
        for (int c = 0; c < 3; ++c){
            scV[c][nt] = __builtin_amdgcn_mfma_f32_16x16x32_bf16(fV[c][0], PB[vb+(nt*2+0)*64+lane], z, 0,0,0);
            scV[c][nt] = __builtin_amdgcn_mfma_f32_16x16x32_bf16(fV[c][1], PB[vb+(nt*2+1)*64+lane], scV[c][nt], 0,0,0);
        }
        const int g = nt*16 + mcol;
        float w0 = wps[spec*320 +   0 + g], w1 = wps[spec*320 +  64 + g];
        float w2 = wps[spec*320 + 128 + g], w3 = wps[spec*320 + 192 + g];
        float w4 = wps[spec*320 + 256 + g];
        float u0 = wpv[spec*256 +   0 + g], u1 = wpv[spec*256 +  64 + g];
        float u2 = wpv[spec*256 + 128 + g], u3 = wpv[spec*256 + 192 + g];
        #pragma unroll
        for (int r = 0; r < 4; ++r){
            float A  = Ais[r]    * kINV_AVG;
            float a0 = Aiv[0][r] * kINV_AVG;
            float a1 = Aiv[1][r] * kINV_AVG;
            float a2 = Aiv[2][r] * kINV_AVG;
            float d   = a0*a0 + a1*a1 + a2*a2;
            float as2 = A*A;
            float Bs  = w0*A + w1*as2 + w2*d + w3*as2*A + w4*A*d;
            float gg  = u0 + u1*A + u2*as2 + u3*d;
            const int row = quad*4 + r;
            Bt[w][0][row*72 + g] = f2b(Bs);
            Bt[w][1][row*72 + g] = f2b(gg*a0);
            Bt[w][2][row*72 + g] = f2b(gg*a1);
            Bt[w][3][row*72 + g] = f2b(gg*a2);
        }
    }

    short8 bS[2], bV[3][2];
    #pragma unroll
    for (int ks = 0; ks < 2; ++ks){
        bS[ks] = *(const short8*)&Bt[w][0][mcol*72 + ks*32 + quad*8];
        #pragma unroll
        for (int c = 0; c < 3; ++c)
            bV[c][ks] = *(const short8*)&Bt[w][1+c][mcol*72 + ks*32 + quad*8];
    }

    float* out_node = out;
    float* out_s    = out + NNODES;
    float* out_v    = out + NNODES + NNODES*64;
    int ndr[4];
    #pragma unroll
    for (int r = 0; r < 4; ++r) ndr[r] = perm[t*16 + quad*4 + r];
    float4v rd = {0.f,0.f,0.f,0.f};
    #pragma unroll
    for (int nt = 0; nt < 4; ++nt){
        float4v oS = scS[nt];
        oS = __builtin_amdgcn_mfma_f32_16x16x32_bf16(bS[0], PB[CWps+(nt*2+0)*64+lane], oS, 0,0,0);
        oS = __builtin_amdgcn_mfma_f32_16x16x32_bf16(bS[1], PB[CWps+(nt*2+1)*64+lane], oS, 0,0,0);
        float4v oV[3];
        #pragma unroll
        for (int c = 0; c < 3; ++c){
            oV[c] = scV[c][nt];
            oV[c] = __builtin_amdgcn_mfma_f32_16x16x32_bf16(bV[c][0], PB[CWpv+(nt*2+0)*64+lane], oV[c], 0,0,0);
            oV[c] = __builtin_amdgcn_mfma_f32_16x16x32_bf16(bV[c][1], PB[CWpv+(nt*2+1)*64+lane], oV[c], 0,0,0);
        }
        const int g = nt*16 + mcol;
        float wr = Wread[g];
        #pragma unroll
        for (int r = 0; r < 4; ++r){
            if (ndr[r] >= 0){
                out_s[ndr[r]*64 + g] = oS[r];
                #pragma unroll
                for (int c = 0; c < 3; ++c) out_v[(ndr[r]*64 + g)*3 + c] = oV[c][r];
            }
            rd[r] += oS[r] * wr;
        }
    }
    #pragma unroll
    for (int off = 1; off < 16; off <<= 1){
        #pragma unroll
        for (int r = 0; r < 4; ++r) rd[r] += __shfl_xor(rd[r], off);
    }
    if (mcol == 0){
        #pragma unroll
        for (int r = 0; r < 4; ++r) if (ndr[r] >= 0) out_node[ndr[r]] = rd[r];
    }
}

extern "C" void kernel_launch(void* const* d_in, const int* in_sizes, int n_in,
                              void* d_out, int out_size, void* d_ws, size_t ws_size,
                              hipStream_t stream)
{
    (void)in_sizes; (void)n_in; (void)out_size; (void)ws_size;
    const float* s    = (const float*)d_in[0];
    const float* v    = (const float*)d_in[1];
    const float* Y1   = (const float*)d_in[2];
    const float* ef   = (const float*)d_in[3];
    const int* specie = (const int*)d_in[4];
    const int* senders   = (const int*)d_in[5];
    const int* receivers = (const int*)d_in[6];
    const float* Wls  = (const float*)d_in[7];
    const float* Wlv  = (const float*)d_in[8];
    const float* Wss  = (const float*)d_in[9];
    const float* Wsv  = (const float*)d_in[10];
    const float* Wr1  = (const float*)d_in[11];
    const float* Wr2  = (const float*)d_in[12];
    const float* Wis  = (const float*)d_in[13];
    const float* Wiv  = (const float*)d_in[14];
    const float* wps  = (const float*)d_in[15];
    const float* wpv  = (const float*)d_in[16];
    const float* Wps  = (const float*)d_in[17];
    const float* Wpv  = (const float*)d_in[18];
    const float* Wrd  = (const float*)d_in[19];

    float* out = (float*)d_out;
    // d_out scratch (all consumed by kedge2 before knodeC2 overwrites):
    //   t_sv  floats [20000, 2,580,000)   packed bf16 sender feats (10.24 MB)
    //   ecnt  floats [2.60M, 2.62M)       histogram -> cursor (20000 ints)
    //   eperm floats [2.624M, 2.944M)     receiver-sorted edge ids
    //   esrt  floats [2.944M, 4.544M)     sorted 20 B records {snd,rcv,y0,y1,y2}
    //   (d_out capacity = 20000*257 = 5.14M floats)
    unsigned short* t_sv = (unsigned short*)(out + NNODES);
    int* ecnt  = (int*)(out + 2600000);
    int* eperm = (int*)(out + 2624000);
    int* esrt  = (int*)(out + 2944000);

    // ws layout (total 31,067,824 B ~= 29.6 MiB, proven OK in R13/R14):
    //  [0, 253952)              bf16 fragment pool P
    //  [262144, 20742144)       Ah fp32 accumulator [N][4][64]
    //  [20742144, +80640)       perm[20160]
    //  [20822784, +5040)        tspec[1260]
    //  [20827824, +2560000)     s_bf [N][64] bf16 raw-input fragments
    //  [23387824, +7680000)     v_bf [N][3][64] bf16 raw-input fragments
    char* ws = (char*)d_ws;
    unsigned short* P = (unsigned short*)ws;
    float* Ahf  = (float*)(ws + 262144);
    int* perm   = (int*)(ws + 20742144);
    int* tspec  = (int*)(ws + 20822784);
    unsigned short* s_bf = (unsigned short*)(ws + 20827824);
    unsigned short* v_bf = (unsigned short*)(ws + 23387824);

    kprep<<<63, 256, 0, stream>>>(specie, Wr2, Wls, Wlv, Wis, Wiv, Wps, Wpv,
                                  Wss, Wsv, P, perm, tspec, ecnt);
    knodeA2<<<313, 256, 0, stream>>>(s, v, P, receivers, ecnt, t_sv, s_bf, v_bf,
                                     (float4v*)Ahf);
    kscan<<<1, 256, 0, stream>>>(ecnt);
    kscat<<<1250, 256, 0, stream>>>(receivers, senders, Y1, ecnt, eperm, esrt);
    kedge2<<<5000, 256, 0, stream>>>(ef, Wr1, P + CW2*8, t_sv, eperm, esrt, Ahf);
    knodeC2<<<315, 256, 0, stream>>>(s_bf, v_bf, Ahf, P, perm, tspec, wps, wpv, Wrd, out);
}